// Round 11
// baseline (183.185 us; speedup 1.0000x reference)
//
#include <hip/hip_runtime.h>
#include <hip/hip_bf16.h>

typedef __hip_bfloat16 bf16;
typedef __fp16 h2 __attribute__((ext_vector_type(2)));   // matches V2h of amdgcn builtins

__device__ __forceinline__ float bf2f(bf16 h) { return __bfloat162float(h); }
__device__ __forceinline__ bf16 us2bf(unsigned short u){ union{unsigned short s; bf16 h;}v; v.s=u; return v.h; }
__device__ __forceinline__ float asf(unsigned u){ union{unsigned u; float f;}v; v.u=u; return v.f; }
__device__ __forceinline__ h2 uh(unsigned u){ union{unsigned u; h2 h;}v; v.u=u; return v.h; }
__device__ __forceinline__ unsigned pkh(float a, float b){ union{h2 h; unsigned u;}v; v.h=__builtin_amdgcn_cvt_pkrtz(a,b); return v.u; }
__device__ __forceinline__ unsigned short f2bu(float a){ union{bf16 h; unsigned short u;}v; v.h=__float2bfloat16(a); return v.u; }
__device__ __forceinline__ unsigned pkbf(float a, float b){ return ((unsigned)f2bu(b) << 16) | (unsigned)f2bu(a); }
#define FDOT2(va,vb,acc) __builtin_amdgcn_fdot2((va),(vb),(acc),false)

#define HH 128
#define WW 128
#define HS 512
#define WSZ 512

// ---- ws dword-offset layout ----
#define O_OFFTAB 0        // 32 f32
#define O_TB     32       // 3 f32
#define O_TW2    64       // 864 u32: tail weights f16 pairs [o][j][cpair]
#define O_CWC2   1024     // 4096 u32: f16 pairs [cls][cp][k]
#define O_W2P    5120     // 1728 u32: f16 pairs [cls][j][o][kpair]
#define O_FEAT   8192     // 524288 u32: feat packed f16 pairs, HWC [px][cp]
#define O_PRED   1056768  // 524288 u32: bf16x4-packed pred, block-sorted [blk][pi]

// k_prep LDS pool carve (f32 units)
#define SH_W2T 0          // 64*65 transposed w2
#define SH_WE  4160       // 2048
#define SH_WC  6208       // 2048
#define SH_TW  8256       // 1728
#define SH_OW  9984       // 128
#define SH_RW  10112      // 256
#define SH_END 10368

// class-sorted halo decode prefix for 10x10 halo (classes by ((p+3)&3))
// ny = [3,2,2,3] (a), nx = [3,2,2,3] (b); counts = ny*nx
__constant__ int PREF3[16] = {0,9,15,21,30,36,40,44,50,56,60,64,70,79,85,91};

__device__ __forceinline__ float rdin(const void* p, int i, bool f32m) {
  return f32m ? ((const float*)p)[i] : bf2f(((const bf16*)p)[i]);
}
__device__ __forceinline__ float rdw(const void* p, int i, bool f32m) {
  if (f32m) return ((const float*)p)[i];
  unsigned u = ((const unsigned*)p)[i>>1];
  return asf((i&1) ? (u & 0xffff0000u) : (u<<16));
}
__device__ __forceinline__ bool sniff_f32(const void* inp) {
  int lane = threadIdx.x & 63;
  unsigned short u = ((const unsigned short*)inp)[2*lane];
  float v = bf2f(us2bf(u));
  bool ok = (v == v) && (fabsf(v) < 64.0f);
  return __popcll(__ballot(ok)) < 48;
}
__device__ __forceinline__ unsigned blend4(unsigned a, unsigned b, unsigned c, unsigned d,
                                           h2 W00, h2 W01, h2 W10, h2 W11) {
  h2 f = uh(a)*W00 + uh(b)*W01 + uh(c)*W10 + uh(d)*W11;   // v_pk_fma_f16
  union{h2 h; unsigned u;} v; v.h = f; return v.u;
}

// ==== K1: encoder conv (f16-packed feat) + per-class MLP/weights (LDS-staged) ====
__global__ __launch_bounds__(256) void k_prep(
    const void* __restrict__ inp, const void* __restrict__ encw, const void* __restrict__ encb,
    const void* __restrict__ w1, const void* __restrict__ b1,
    const void* __restrict__ w2, const void* __restrict__ b2,
    const void* __restrict__ rw, const void* __restrict__ rb,
    const void* __restrict__ ow, const void* __restrict__ ob,
    const void* __restrict__ tw, const void* __restrict__ tb,
    const void* __restrict__ wc, const void* __restrict__ we,
    float* __restrict__ ws) {
  __shared__ float shpool[SH_END];
  __shared__ float sh1[64];
  __shared__ float sh2[64];
  __shared__ float shr[4];
  __shared__ float shcwe[512];
  bool f32m = sniff_f32(inp);
  int b = blockIdx.x, t = threadIdx.x;
  unsigned* wsu = (unsigned*)ws;

  if (b < 256) {
    // ---- encoder conv 3->64: block = (channel-group g, 256-px tile) ----
    int g = b >> 6;                 // oc [g*16, g*16+16)
    int px = (b & 63)*256 + t;
    float* shw = shpool;            // 432
    float* shb = shpool + 432;      // 16
    for (int i = t; i < 432; i += 256) shw[i] = rdw(encw, g*432 + i, f32m);
    if (t < 16) shb[t] = rdw(encb, g*16 + t, f32m);
    __syncthreads();
    int x = px & 127, y = px >> 7;
    float tp[27];
    #pragma unroll
    for (int ic = 0; ic < 3; ic++)
      #pragma unroll
      for (int dy = 0; dy < 3; dy++) {
        int yy = y + dy - 1;
        #pragma unroll
        for (int dx = 0; dx < 3; dx++) {
          int xx = x + dx - 1;
          bool ok = (yy >= 0) & (yy < 128) & (xx >= 0) & (xx < 128);
          tp[ic*9 + dy*3 + dx] = ok ? rdin(inp, ic*16384 + yy*128 + xx, f32m) : 0.0f;
        }
      }
    unsigned e[8];
    #pragma unroll
    for (int o4 = 0; o4 < 4; o4++) {
      float a[4];
      #pragma unroll
      for (int oo = 0; oo < 4; oo++) {
        int o2 = o4*4 + oo;
        float acc = shb[o2];
        #pragma unroll
        for (int kk = 0; kk < 27; kk++) acc = fmaf(shw[o2*27 + kk], tp[kk], acc);
        a[oo] = acc;
      }
      e[o4*2]   = pkh(a[0], a[1]);
      e[o4*2+1] = pkh(a[2], a[3]);
    }
    uint4* outp = (uint4*)(wsu + O_FEAT + px*32 + g*8);
    outp[0] = make_uint4(e[0], e[1], e[2], e[3]);
    outp[1] = make_uint4(e[4], e[5], e[6], e[7]);
  } else if (b < 272) {
    // ---- per-class MLP -> off, r; fold into CWC2 / W2P (weights LDS-staged) ----
    int cls = b - 256;
    for (int i = t; i < 4096; i += 256) shpool[SH_W2T + (i & 63)*65 + (i >> 6)] = rdw(w2, i, f32m);
    for (int i = t; i < 2048; i += 256) { shpool[SH_WE + i] = rdw(we, i, f32m); shpool[SH_WC + i] = rdw(wc, i, f32m); }
    for (int i = t; i < 1728; i += 256) shpool[SH_TW + i] = rdw(tw, i, f32m);
    for (int i = t; i < 128; i += 256)  shpool[SH_OW + i] = rdw(ow, i, f32m);
    for (int i = t; i < 256; i += 256)  shpool[SH_RW + i] = rdw(rw, i, f32m);
    if (t < 64) {
      float mcls = (float)(cls >> 2), ncls = (float)(cls & 3);
      float chv = (mcls + 0.5f)*0.25f - 0.5f;
      float cwv = (ncls + 0.5f)*0.25f - 0.5f;
      float s1 = rdw(w1,t*4+0,f32m)*0.25f + rdw(w1,t*4+1,f32m)*0.25f
               + rdw(w1,t*4+2,f32m)*chv + rdw(w1,t*4+3,f32m)*cwv + rdw(b1,t,f32m);
      sh1[t] = fmaxf(s1, 0.0f);
    }
    __syncthreads();
    if (t < 64) {
      float s2 = rdw(b2,t,f32m);
      for (int i = 0; i < 64; i++) s2 = fmaf(shpool[SH_W2T + i*65 + t], sh1[i], s2);
      sh2[t] = fmaxf(s2, 0.0f);
    }
    __syncthreads();
    if (t < 2) {
      float a = rdw(ob,t,f32m);
      for (int i = 0; i < 64; i++) a = fmaf(shpool[SH_OW + t*64 + i], sh2[i], a);
      ws[O_OFFTAB + cls*2 + t] = a;
    } else if (t < 6) {
      int e = t - 2;
      float a = rdw(rb,e,f32m);
      for (int i = 0; i < 64; i++) a = fmaf(shpool[SH_RW + e*64 + i], sh2[i], a);
      shr[e] = 1.0f / (1.0f + expf(-a));
    }
    __syncthreads();
    float r0 = shr[0], r1 = shr[1], r2 = shr[2], r3 = shr[3];
    for (int idx = t; idx < 512; idx += 256) {
      float a =       r0 * shpool[SH_WE + idx];
      a = fmaf(r1, shpool[SH_WE +  512 + idx], a);
      a = fmaf(r2, shpool[SH_WE + 1024 + idx], a);
      a = fmaf(r3, shpool[SH_WE + 1536 + idx], a);
      shcwe[idx] = a;
    }
    unsigned* wcw = wsu + O_CWC2 + cls*256;
    for (int idx = t; idx < 256; idx += 256) {
      int cp = idx >> 3, k = idx & 7;
      float lo =       r0 * shpool[SH_WC +        k*64 + 2*cp];
      lo = fmaf(r1, shpool[SH_WC +  512 + k*64 + 2*cp], lo);
      lo = fmaf(r2, shpool[SH_WC + 1024 + k*64 + 2*cp], lo);
      lo = fmaf(r3, shpool[SH_WC + 1536 + k*64 + 2*cp], lo);
      float hi =       r0 * shpool[SH_WC +        k*64 + 2*cp + 1];
      hi = fmaf(r1, shpool[SH_WC +  512 + k*64 + 2*cp + 1], hi);
      hi = fmaf(r2, shpool[SH_WC + 1024 + k*64 + 2*cp + 1], hi);
      hi = fmaf(r3, shpool[SH_WC + 1536 + k*64 + 2*cp + 1], hi);
      wcw[idx] = pkh(lo, hi);
    }
    __syncthreads();
    unsigned* wpp = wsu + O_W2P;
    for (int idx = t; idx < 108; idx += 256) {
      int j = idx / 12, rem = idx - j*12, o2 = rem >> 2, kp = rem & 3;
      float alo = 0.0f, ahi = 0.0f;
      for (int c = 0; c < 64; c++) {
        float tv = shpool[SH_TW + (o2*64 + c)*9 + j];
        alo = fmaf(tv, shcwe[c*8 + 2*kp],     alo);
        ahi = fmaf(tv, shcwe[c*8 + 2*kp + 1], ahi);
      }
      wpp[(cls*9 + j)*12 + o2*4 + kp] = pkh(alo, ahi);
    }
  } else {
    for (int idx = t; idx < 864; idx += 256) {
      int o2 = idx / 288, rem = idx - o2*288, j = rem >> 5, cp = rem & 31;
      unsigned d = pkh(rdw(tw, (o2*64 + 2*cp    )*9 + j, f32m),
                       rdw(tw, (o2*64 + 2*cp + 1)*9 + j, f32m));
      (wsu + O_TW2)[idx] = d;
    }
    if (t < 3) ws[O_TB + t] = rdin(tb, t, f32m);
  }
}

// ==== K2: fused main+tail, tile 8x8, halo 10x10, row layout shd[pos][36] ====
// shd row: dwords 0..31 = fc f16 pairs (64 ch), 32..35 = mid f16 pairs. stride 36 dw = 144 B (16B-aligned).
__global__ __launch_bounds__(256) void k_maintail(const float* __restrict__ ws, unsigned* __restrict__ pred4) {
  __shared__ __align__(16) unsigned shd[100*36];   // 14400 B
  __shared__ unsigned short scls[100];
  __shared__ float spart[3*192];                   // splits 1..3 partials
  const unsigned* wsu = (const unsigned*)ws;
  int blk = blockIdx.x;                            // 0..4095
  int xcd = blk & 7, local = blk >> 3;             // XCD-banded for L2 locality
  int ty0 = (xcd*8 + (local >> 6)) * 8;
  int tx0 = (local & 63) * 8;
  int t = threadIdx.x;
  int q = t & 1;                                   // channel-half (32 ch each)
  const uint4* F2 = (const uint4*)(wsu + O_FEAT);

  int s = t >> 1;                                  // 200 lane-tasks, single pass
  if (s < 100) {
    int cls = 0;
    #pragma unroll
    for (int i = 1; i < 16; i++) cls += (s >= PREF3[i]) ? 1 : 0;
    int j = s - PREF3[cls];
    int a = cls >> 2, bb = cls & 3;
    int nx = ((bb == 0) | (bb == 3)) ? 3 : 2;
    int jy = (nx == 3) ? ((j*11) >> 5) : (j >> 1);
    int jx = j - jy*nx;
    int py = ((a + 1) & 3) + 4*jy;
    int px = ((bb + 1) & 3) + 4*jx;
    int pos = py*10 + px;
    unsigned* row = &shd[pos*36 + q*16];
    int gy = ty0 - 1 + py, gx = tx0 - 1 + px;
    if ((gy < 0) | (gy >= HS) | (gx < 0) | (gx >= WSZ)) {
      if (q == 0) scls[pos] = 0;
      ((uint4*)row)[0] = make_uint4(0,0,0,0);
      ((uint4*)row)[1] = make_uint4(0,0,0,0);
      ((uint4*)row)[2] = make_uint4(0,0,0,0);
      ((uint4*)row)[3] = make_uint4(0,0,0,0);
      shd[pos*36 + 32 + q*2 + 0] = 0u;
      shd[pos*36 + 32 + q*2 + 1] = 0u;
    } else {
      if (q == 0) scls[pos] = (unsigned short)cls;
      float off0 = ws[O_OFFTAB + cls*2 + 0];
      float off1 = ws[O_OFFTAB + cls*2 + 1];
      float gxf = (((float)gx + 0.5f)*0.25f - 0.5f)*(2.0f/127.0f) - 1.0f + off0*(2.0f/127.0f);
      float gyf = (((float)gy + 0.5f)*0.25f - 0.5f)*(2.0f/127.0f) - 1.0f + off1*(2.0f/127.0f);
      float sx = (gxf + 1.0f)*0.5f*127.0f;
      float sy = (gyf + 1.0f)*0.5f*127.0f;
      float x0f = floorf(sx), y0f = floorf(sy);
      float fx = sx - x0f, fy = sy - y0f;
      int ix0 = (int)x0f, iy0 = (int)y0f;
      int ix1 = ix0 + 1, iy1 = iy0 + 1;
      float wx0 = 1.0f - fx, wy0 = 1.0f - fy;
      float w00 = wy0*wx0, w01 = wy0*fx, w10 = fy*wx0, w11 = fy*fx;
      bool vx0 = (ix0 >= 0) & (ix0 < WW), vx1 = (ix1 >= 0) & (ix1 < WW);
      bool vy0 = (iy0 >= 0) & (iy0 < HH), vy1 = (iy1 >= 0) & (iy1 < HH);
      if (!(vy0 & vx0)) w00 = 0.0f;
      if (!(vy0 & vx1)) w01 = 0.0f;
      if (!(vy1 & vx0)) w10 = 0.0f;
      if (!(vy1 & vx1)) w11 = 0.0f;
      int cx0 = min(max(ix0, 0), WW-1), cx1 = min(max(ix1, 0), WW-1);
      int cy0 = min(max(iy0, 0), HH-1), cy1 = min(max(iy1, 0), HH-1);
      int b00 = (cy0*WW + cx0)*8 + q*4, b01 = (cy0*WW + cx1)*8 + q*4;
      int b10 = (cy1*WW + cx0)*8 + q*4, b11 = (cy1*WW + cx1)*8 + q*4;

      // batch all 16 tap loads (forced wide load window)
      uint4 A0 = F2[b00+0], A1 = F2[b00+1], A2 = F2[b00+2], A3 = F2[b00+3];
      uint4 B0 = F2[b01+0], B1 = F2[b01+1], B2 = F2[b01+2], B3 = F2[b01+3];
      uint4 C0 = F2[b10+0], C1 = F2[b10+1], C2 = F2[b10+2], C3 = F2[b10+3];
      uint4 D0 = F2[b11+0], D1 = F2[b11+1], D2 = F2[b11+2], D3 = F2[b11+3];

      h2 W00 = { (__fp16)w00, (__fp16)w00 };
      h2 W01 = { (__fp16)w01, (__fp16)w01 };
      h2 W10 = { (__fp16)w10, (__fp16)w10 };
      h2 W11 = { (__fp16)w11, (__fp16)w11 };

      unsigned fp[16];
      fp[ 0] = blend4(A0.x,B0.x,C0.x,D0.x,W00,W01,W10,W11);
      fp[ 1] = blend4(A0.y,B0.y,C0.y,D0.y,W00,W01,W10,W11);
      fp[ 2] = blend4(A0.z,B0.z,C0.z,D0.z,W00,W01,W10,W11);
      fp[ 3] = blend4(A0.w,B0.w,C0.w,D0.w,W00,W01,W10,W11);
      fp[ 4] = blend4(A1.x,B1.x,C1.x,D1.x,W00,W01,W10,W11);
      fp[ 5] = blend4(A1.y,B1.y,C1.y,D1.y,W00,W01,W10,W11);
      fp[ 6] = blend4(A1.z,B1.z,C1.z,D1.z,W00,W01,W10,W11);
      fp[ 7] = blend4(A1.w,B1.w,C1.w,D1.w,W00,W01,W10,W11);
      fp[ 8] = blend4(A2.x,B2.x,C2.x,D2.x,W00,W01,W10,W11);
      fp[ 9] = blend4(A2.y,B2.y,C2.y,D2.y,W00,W01,W10,W11);
      fp[10] = blend4(A2.z,B2.z,C2.z,D2.z,W00,W01,W10,W11);
      fp[11] = blend4(A2.w,B2.w,C2.w,D2.w,W00,W01,W10,W11);
      fp[12] = blend4(A3.x,B3.x,C3.x,D3.x,W00,W01,W10,W11);
      fp[13] = blend4(A3.y,B3.y,C3.y,D3.y,W00,W01,W10,W11);
      fp[14] = blend4(A3.z,B3.z,C3.z,D3.z,W00,W01,W10,W11);
      fp[15] = blend4(A3.w,B3.w,C3.w,D3.w,W00,W01,W10,W11);

      // 4 vector LDS writes (b128), conflict-free with 144B row stride
      ((uint4*)row)[0] = make_uint4(fp[0],  fp[1],  fp[2],  fp[3]);
      ((uint4*)row)[1] = make_uint4(fp[4],  fp[5],  fp[6],  fp[7]);
      ((uint4*)row)[2] = make_uint4(fp[8],  fp[9],  fp[10], fp[11]);
      ((uint4*)row)[3] = make_uint4(fp[12], fp[13], fp[14], fp[15]);

      const uint4* CWv = (const uint4*)(wsu + O_CWC2 + cls*256) + q*32;
      float mid[8] = {0,0,0,0,0,0,0,0};
      #pragma unroll
      for (int i = 0; i < 16; i++) {
        uint4 w0 = CWv[i*2], w1 = CWv[i*2+1];
        h2 f = uh(fp[i]);
        mid[0] = FDOT2(f, uh(w0.x), mid[0]); mid[1] = FDOT2(f, uh(w0.y), mid[1]);
        mid[2] = FDOT2(f, uh(w0.z), mid[2]); mid[3] = FDOT2(f, uh(w0.w), mid[3]);
        mid[4] = FDOT2(f, uh(w1.x), mid[4]); mid[5] = FDOT2(f, uh(w1.y), mid[5]);
        mid[6] = FDOT2(f, uh(w1.z), mid[6]); mid[7] = FDOT2(f, uh(w1.w), mid[7]);
      }
      #pragma unroll
      for (int k = 0; k < 8; k++) mid[k] += __shfl_xor(mid[k], 1);
      shd[pos*36 + 32 + q*2 + 0] = pkh(mid[q*4+0], mid[q*4+1]);
      shd[pos*36 + 32 + q*2 + 1] = pkh(mid[q*4+2], mid[q*4+3]);
    }
  }
  __syncthreads();

  // ---- tail: wave-uniform 4-way split (split = wave idx) ----
  int split = t >> 6, pi = t & 63;
  int tx = pi & 7, ty = pi >> 3;
  const unsigned* TW2 = wsu + O_TW2;
  float a0, a1, a2;
  if (split == 0) { a0 = ws[O_TB+0]; a1 = ws[O_TB+1]; a2 = ws[O_TB+2]; }
  else            { a0 = 0.0f; a1 = 0.0f; a2 = 0.0f; }
  const int JB[4] = {0, 2, 5, 7};
  const int JE[4] = {2, 5, 7, 9};
  #pragma unroll
  for (int j = 0; j < 9; j++) {
    int dy = j / 3, dx = j - dy*3;
    int pp = (ty + dy)*10 + (tx + dx);
    // fc part: this split's 8 channel-pairs as 2 x ds_read_b128
    const uint4* frow = (const uint4*)&shd[pp*36 + split*8];
    uint4 f0 = frow[0], f1 = frow[1];
    int cb = split*8;
    a0 = FDOT2(uh(f0.x), uh(TW2[(0*9+j)*32 + cb+0]), a0);
    a0 = FDOT2(uh(f0.y), uh(TW2[(0*9+j)*32 + cb+1]), a0);
    a0 = FDOT2(uh(f0.z), uh(TW2[(0*9+j)*32 + cb+2]), a0);
    a0 = FDOT2(uh(f0.w), uh(TW2[(0*9+j)*32 + cb+3]), a0);
    a0 = FDOT2(uh(f1.x), uh(TW2[(0*9+j)*32 + cb+4]), a0);
    a0 = FDOT2(uh(f1.y), uh(TW2[(0*9+j)*32 + cb+5]), a0);
    a0 = FDOT2(uh(f1.z), uh(TW2[(0*9+j)*32 + cb+6]), a0);
    a0 = FDOT2(uh(f1.w), uh(TW2[(0*9+j)*32 + cb+7]), a0);
    a1 = FDOT2(uh(f0.x), uh(TW2[(1*9+j)*32 + cb+0]), a1);
    a1 = FDOT2(uh(f0.y), uh(TW2[(1*9+j)*32 + cb+1]), a1);
    a1 = FDOT2(uh(f0.z), uh(TW2[(1*9+j)*32 + cb+2]), a1);
    a1 = FDOT2(uh(f0.w), uh(TW2[(1*9+j)*32 + cb+3]), a1);
    a1 = FDOT2(uh(f1.x), uh(TW2[(1*9+j)*32 + cb+4]), a1);
    a1 = FDOT2(uh(f1.y), uh(TW2[(1*9+j)*32 + cb+5]), a1);
    a1 = FDOT2(uh(f1.z), uh(TW2[(1*9+j)*32 + cb+6]), a1);
    a1 = FDOT2(uh(f1.w), uh(TW2[(1*9+j)*32 + cb+7]), a1);
    a2 = FDOT2(uh(f0.x), uh(TW2[(2*9+j)*32 + cb+0]), a2);
    a2 = FDOT2(uh(f0.y), uh(TW2[(2*9+j)*32 + cb+1]), a2);
    a2 = FDOT2(uh(f0.z), uh(TW2[(2*9+j)*32 + cb+2]), a2);
    a2 = FDOT2(uh(f0.w), uh(TW2[(2*9+j)*32 + cb+3]), a2);
    a2 = FDOT2(uh(f1.x), uh(TW2[(2*9+j)*32 + cb+4]), a2);
    a2 = FDOT2(uh(f1.y), uh(TW2[(2*9+j)*32 + cb+5]), a2);
    a2 = FDOT2(uh(f1.z), uh(TW2[(2*9+j)*32 + cb+6]), a2);
    a2 = FDOT2(uh(f1.w), uh(TW2[(2*9+j)*32 + cb+7]), a2);
    // mid part for this split's j-range
    if (j >= JB[split] && j < JE[split]) {
      int cl = scls[pp];
      uint4 mv = *(const uint4*)&shd[pp*36 + 32];
      const uint4* Wp = (const uint4*)(wsu + O_W2P) + (cl*9 + j)*3;
      uint4 w0 = Wp[0], w1 = Wp[1], w2 = Wp[2];
      h2 m0 = uh(mv.x), m1 = uh(mv.y), m2 = uh(mv.z), m3 = uh(mv.w);
      a0 = FDOT2(m0, uh(w0.x), a0); a0 = FDOT2(m1, uh(w0.y), a0);
      a0 = FDOT2(m2, uh(w0.z), a0); a0 = FDOT2(m3, uh(w0.w), a0);
      a1 = FDOT2(m0, uh(w1.x), a1); a1 = FDOT2(m1, uh(w1.y), a1);
      a1 = FDOT2(m2, uh(w1.z), a1); a1 = FDOT2(m3, uh(w1.w), a1);
      a2 = FDOT2(m0, uh(w2.x), a2); a2 = FDOT2(m1, uh(w2.y), a2);
      a2 = FDOT2(m2, uh(w2.z), a2); a2 = FDOT2(m3, uh(w2.w), a2);
    }
  }
  if (split != 0) {
    float* sp = spart + (split-1)*192 + pi*3;
    sp[0] = a0; sp[1] = a1; sp[2] = a2;
  }
  __syncthreads();
  if (split == 0) {
    #pragma unroll
    for (int k = 0; k < 3; k++) {
      const float* sp = spart + k*192 + pi*3;
      a0 += sp[0]; a1 += sp[1]; a2 += sp[2];
    }
    ((uint2*)pred4)[blk*64 + pi] = make_uint2(pkbf(a0, a1), pkbf(a2, 0.0f));
  }
}

// ==== K3: query gather ====
__global__ __launch_bounds__(256) void k_gather(const void* __restrict__ inp,
                                                const void* __restrict__ coord, const void* __restrict__ cell,
                                                const float* __restrict__ ws, void* __restrict__ outp) {
  bool f32m = sniff_f32(inp);
  const uint2* pred4 = (const uint2*)((const unsigned*)ws + O_PRED);
  int q = blockIdx.x*256 + threadIdx.x;
  float cy, cx, ly, lx;
  if (f32m) {
    float2 c = ((const float2*)coord)[q]; cy = c.x; cx = c.y;
    float2 l = ((const float2*)cell)[q];  ly = l.x; lx = l.y;
  } else {
    unsigned cu = ((const unsigned*)coord)[q]; cy = asf(cu<<16); cx = asf(cu & 0xffff0000u);
    unsigned lu = ((const unsigned*)cell)[q];  ly = asf(lu<<16); lx = asf(lu & 0xffff0000u);
  }
  float gyq = fminf(fmaxf(cy - ly*0.5f + 1e-6f, -1.0f + 1e-6f), 1.0f - 1e-6f);
  float gxq = fminf(fmaxf(cx - lx*0.5f + 1e-6f, -1.0f + 1e-6f), 1.0f - 1e-6f);
  int xi = (int)rintf((gxq + 1.0f)*0.5f*511.0f);
  int yi = (int)rintf((gyq + 1.0f)*0.5f*511.0f);
  xi = min(max(xi, 0), WSZ-1);
  yi = min(max(yi, 0), HS-1);
  // invert 8x8 block-sorted layout
  int row = yi >> 3, col = xi >> 3;
  int xcd = row >> 3;
  int local = (row & 7)*64 + col;
  int blk = local*8 + xcd;
  int pi = (yi & 7)*8 + (xi & 7);
  uint2 d = pred4[blk*64 + pi];
  float v0 = asf(d.x << 16), v1 = asf(d.x & 0xffff0000u), v2 = asf(d.y << 16);
  if (f32m) {
    float* o = (float*)outp;
    o[q*3 + 0] = v0; o[q*3 + 1] = v1; o[q*3 + 2] = v2;
  } else {
    bf16* o = (bf16*)outp;
    o[q*3 + 0] = __float2bfloat16(v0);
    o[q*3 + 1] = __float2bfloat16(v1);
    o[q*3 + 2] = __float2bfloat16(v2);
  }
}

extern "C" void kernel_launch(void* const* d_in, const int* in_sizes, int n_in,
                              void* d_out, int out_size, void* d_ws, size_t ws_size,
                              hipStream_t stream) {
  const void* inp   = d_in[0];
  const void* coord = d_in[1];
  const void* cell  = d_in[2];
  const void* encw  = d_in[3];
  const void* encb  = d_in[4];
  const void* w1    = d_in[5];
  const void* b1    = d_in[6];
  const void* w2    = d_in[7];
  const void* b2    = d_in[8];
  const void* rw    = d_in[9];
  const void* rb    = d_in[10];
  const void* ow    = d_in[11];
  const void* ob    = d_in[12];
  const void* tw    = d_in[13];
  const void* tb    = d_in[14];
  const void* wc    = d_in[15];
  const void* we    = d_in[16];

  float* wsf = (float*)d_ws;
  unsigned* pred4 = (unsigned*)wsf + O_PRED;

  k_prep<<<273, 256, 0, stream>>>(inp, encw, encb, w1, b1, w2, b2, rw, rb, ow, ob, tw, tb, wc, we, wsf);
  k_maintail<<<4096, 256, 0, stream>>>(wsf, pred4);
  k_gather<<<1024, 256, 0, stream>>>(inp, coord, cell, wsf, d_out);
}

// Round 12
// 165.369 us; speedup vs baseline: 1.1077x; 1.1077x over previous
//
#include <hip/hip_runtime.h>
#include <hip/hip_bf16.h>

typedef __hip_bfloat16 bf16;
typedef __fp16 h2 __attribute__((ext_vector_type(2)));   // matches V2h of amdgcn builtins

__device__ __forceinline__ float bf2f(bf16 h) { return __bfloat162float(h); }
__device__ __forceinline__ bf16 us2bf(unsigned short u){ union{unsigned short s; bf16 h;}v; v.s=u; return v.h; }
__device__ __forceinline__ float asf(unsigned u){ union{unsigned u; float f;}v; v.u=u; return v.f; }
__device__ __forceinline__ h2 uh(unsigned u){ union{unsigned u; h2 h;}v; v.u=u; return v.h; }
__device__ __forceinline__ unsigned pkh(float a, float b){ union{h2 h; unsigned u;}v; v.h=__builtin_amdgcn_cvt_pkrtz(a,b); return v.u; }
__device__ __forceinline__ unsigned short f2bu(float a){ union{bf16 h; unsigned short u;}v; v.h=__float2bfloat16(a); return v.u; }
__device__ __forceinline__ unsigned pkbf(float a, float b){ return ((unsigned)f2bu(b) << 16) | (unsigned)f2bu(a); }
#define FDOT2(va,vb,acc) __builtin_amdgcn_fdot2((va),(vb),(acc),false)

#define HH 128
#define WW 128
#define HS 512
#define WSZ 512

// ---- ws dword-offset layout ----
#define O_OFFTAB 0        // 32 f32
#define O_TB     32       // 3 f32
#define O_TW2    64       // 864 u32: tail weights f16 pairs [o][j][cpair]
#define O_CWC2   1024     // 4096 u32: f16 pairs [cls][cp][k]
#define O_W2P    5120     // 1728 u32: f16 pairs [cls][j][o][kpair]
#define O_FEAT   8192     // 524288 u32: feat packed f16 pairs, HWC [px][cp]
#define O_PRED   1056768  // 524288 u32: bf16x4-packed pred, block-sorted [blk][pi]

// k_prep LDS pool carve (f32 units)
#define SH_W2T 0          // 64*65 transposed w2
#define SH_WE  4160       // 2048
#define SH_WC  6208       // 2048
#define SH_TW  8256       // 1728
#define SH_OW  9984       // 128
#define SH_RW  10112      // 256
#define SH_END 10368

// class-sorted halo decode prefix for 10x10 halo (classes by ((p+3)&3))
__constant__ int PREF3[16] = {0,9,15,21,30,36,40,44,50,56,60,64,70,79,85,91};

__device__ __forceinline__ float rdin(const void* p, int i, bool f32m) {
  return f32m ? ((const float*)p)[i] : bf2f(((const bf16*)p)[i]);
}
__device__ __forceinline__ float rdw(const void* p, int i, bool f32m) {
  if (f32m) return ((const float*)p)[i];
  unsigned u = ((const unsigned*)p)[i>>1];
  return asf((i&1) ? (u & 0xffff0000u) : (u<<16));
}
__device__ __forceinline__ bool sniff_f32(const void* inp) {
  int lane = threadIdx.x & 63;
  unsigned short u = ((const unsigned short*)inp)[2*lane];
  float v = bf2f(us2bf(u));
  bool ok = (v == v) && (fabsf(v) < 64.0f);
  return __popcll(__ballot(ok)) < 48;
}
__device__ __forceinline__ unsigned blend4(unsigned a, unsigned b, unsigned c, unsigned d,
                                           h2 W00, h2 W01, h2 W10, h2 W11) {
  h2 f = uh(a)*W00 + uh(b)*W01 + uh(c)*W10 + uh(d)*W11;   // v_pk_fma_f16
  union{h2 h; unsigned u;} v; v.h = f; return v.u;
}

// ==== K1: encoder conv (f16-packed feat) + per-class MLP/weights (LDS-staged) ====
__global__ __launch_bounds__(256) void k_prep(
    const void* __restrict__ inp, const void* __restrict__ encw, const void* __restrict__ encb,
    const void* __restrict__ w1, const void* __restrict__ b1,
    const void* __restrict__ w2, const void* __restrict__ b2,
    const void* __restrict__ rw, const void* __restrict__ rb,
    const void* __restrict__ ow, const void* __restrict__ ob,
    const void* __restrict__ tw, const void* __restrict__ tb,
    const void* __restrict__ wc, const void* __restrict__ we,
    float* __restrict__ ws) {
  __shared__ float shpool[SH_END];
  __shared__ float sh1[64];
  __shared__ float sh2[64];
  __shared__ float shr[4];
  __shared__ float shcwe[512];
  bool f32m = sniff_f32(inp);
  int b = blockIdx.x, t = threadIdx.x;
  unsigned* wsu = (unsigned*)ws;

  if (b < 256) {
    // ---- encoder conv 3->64: block = (channel-group g, 256-px tile) ----
    int g = b >> 6;                 // oc [g*16, g*16+16)
    int px = (b & 63)*256 + t;
    float* shw = shpool;            // 432
    float* shb = shpool + 432;      // 16
    for (int i = t; i < 432; i += 256) shw[i] = rdw(encw, g*432 + i, f32m);
    if (t < 16) shb[t] = rdw(encb, g*16 + t, f32m);
    __syncthreads();
    int x = px & 127, y = px >> 7;
    float tp[27];
    #pragma unroll
    for (int ic = 0; ic < 3; ic++)
      #pragma unroll
      for (int dy = 0; dy < 3; dy++) {
        int yy = y + dy - 1;
        #pragma unroll
        for (int dx = 0; dx < 3; dx++) {
          int xx = x + dx - 1;
          bool ok = (yy >= 0) & (yy < 128) & (xx >= 0) & (xx < 128);
          tp[ic*9 + dy*3 + dx] = ok ? rdin(inp, ic*16384 + yy*128 + xx, f32m) : 0.0f;
        }
      }
    unsigned e[8];
    #pragma unroll
    for (int o4 = 0; o4 < 4; o4++) {
      float a[4];
      #pragma unroll
      for (int oo = 0; oo < 4; oo++) {
        int o2 = o4*4 + oo;
        float acc = shb[o2];
        #pragma unroll
        for (int kk = 0; kk < 27; kk++) acc = fmaf(shw[o2*27 + kk], tp[kk], acc);
        a[oo] = acc;
      }
      e[o4*2]   = pkh(a[0], a[1]);
      e[o4*2+1] = pkh(a[2], a[3]);
    }
    uint4* outp = (uint4*)(wsu + O_FEAT + px*32 + g*8);
    outp[0] = make_uint4(e[0], e[1], e[2], e[3]);
    outp[1] = make_uint4(e[4], e[5], e[6], e[7]);
  } else if (b < 272) {
    // ---- per-class MLP -> off, r; fold into CWC2 / W2P (weights LDS-staged) ----
    int cls = b - 256;
    for (int i = t; i < 4096; i += 256) shpool[SH_W2T + (i & 63)*65 + (i >> 6)] = rdw(w2, i, f32m);
    for (int i = t; i < 2048; i += 256) { shpool[SH_WE + i] = rdw(we, i, f32m); shpool[SH_WC + i] = rdw(wc, i, f32m); }
    for (int i = t; i < 1728; i += 256) shpool[SH_TW + i] = rdw(tw, i, f32m);
    for (int i = t; i < 128; i += 256)  shpool[SH_OW + i] = rdw(ow, i, f32m);
    for (int i = t; i < 256; i += 256)  shpool[SH_RW + i] = rdw(rw, i, f32m);
    if (t < 64) {
      float mcls = (float)(cls >> 2), ncls = (float)(cls & 3);
      float chv = (mcls + 0.5f)*0.25f - 0.5f;
      float cwv = (ncls + 0.5f)*0.25f - 0.5f;
      float s1 = rdw(w1,t*4+0,f32m)*0.25f + rdw(w1,t*4+1,f32m)*0.25f
               + rdw(w1,t*4+2,f32m)*chv + rdw(w1,t*4+3,f32m)*cwv + rdw(b1,t,f32m);
      sh1[t] = fmaxf(s1, 0.0f);
    }
    __syncthreads();
    if (t < 64) {
      float s2 = rdw(b2,t,f32m);
      for (int i = 0; i < 64; i++) s2 = fmaf(shpool[SH_W2T + i*65 + t], sh1[i], s2);
      sh2[t] = fmaxf(s2, 0.0f);
    }
    __syncthreads();
    if (t < 2) {
      float a = rdw(ob,t,f32m);
      for (int i = 0; i < 64; i++) a = fmaf(shpool[SH_OW + t*64 + i], sh2[i], a);
      ws[O_OFFTAB + cls*2 + t] = a;
    } else if (t < 6) {
      int e = t - 2;
      float a = rdw(rb,e,f32m);
      for (int i = 0; i < 64; i++) a = fmaf(shpool[SH_RW + e*64 + i], sh2[i], a);
      shr[e] = 1.0f / (1.0f + expf(-a));
    }
    __syncthreads();
    float r0 = shr[0], r1 = shr[1], r2 = shr[2], r3 = shr[3];
    for (int idx = t; idx < 512; idx += 256) {
      float a =       r0 * shpool[SH_WE + idx];
      a = fmaf(r1, shpool[SH_WE +  512 + idx], a);
      a = fmaf(r2, shpool[SH_WE + 1024 + idx], a);
      a = fmaf(r3, shpool[SH_WE + 1536 + idx], a);
      shcwe[idx] = a;
    }
    unsigned* wcw = wsu + O_CWC2 + cls*256;
    for (int idx = t; idx < 256; idx += 256) {
      int cp = idx >> 3, k = idx & 7;
      float lo =       r0 * shpool[SH_WC +        k*64 + 2*cp];
      lo = fmaf(r1, shpool[SH_WC +  512 + k*64 + 2*cp], lo);
      lo = fmaf(r2, shpool[SH_WC + 1024 + k*64 + 2*cp], lo);
      lo = fmaf(r3, shpool[SH_WC + 1536 + k*64 + 2*cp], lo);
      float hi =       r0 * shpool[SH_WC +        k*64 + 2*cp + 1];
      hi = fmaf(r1, shpool[SH_WC +  512 + k*64 + 2*cp + 1], hi);
      hi = fmaf(r2, shpool[SH_WC + 1024 + k*64 + 2*cp + 1], hi);
      hi = fmaf(r3, shpool[SH_WC + 1536 + k*64 + 2*cp + 1], hi);
      wcw[idx] = pkh(lo, hi);
    }
    __syncthreads();
    unsigned* wpp = wsu + O_W2P;
    for (int idx = t; idx < 108; idx += 256) {
      int j = idx / 12, rem = idx - j*12, o2 = rem >> 2, kp = rem & 3;
      float alo = 0.0f, ahi = 0.0f;
      for (int c = 0; c < 64; c++) {
        float tv = shpool[SH_TW + (o2*64 + c)*9 + j];
        alo = fmaf(tv, shcwe[c*8 + 2*kp],     alo);
        ahi = fmaf(tv, shcwe[c*8 + 2*kp + 1], ahi);
      }
      wpp[(cls*9 + j)*12 + o2*4 + kp] = pkh(alo, ahi);
    }
  } else {
    for (int idx = t; idx < 864; idx += 256) {
      int o2 = idx / 288, rem = idx - o2*288, j = rem >> 5, cp = rem & 31;
      unsigned d = pkh(rdw(tw, (o2*64 + 2*cp    )*9 + j, f32m),
                       rdw(tw, (o2*64 + 2*cp + 1)*9 + j, f32m));
      (wsu + O_TW2)[idx] = d;
    }
    if (t < 3) ws[O_TB + t] = rdin(tb, t, f32m);
  }
}

// ==== K2: fused main+tail, tile 8x8, halo 10x10, CWC2 staged in LDS ====
// shd row: dwords 0..31 = fc f16 pairs (64 ch), 32..35 = mid f16 pairs. stride 36 dw = 144 B.
__global__ __launch_bounds__(256) void k_maintail(const float* __restrict__ ws, unsigned* __restrict__ pred4) {
  __shared__ __align__(16) unsigned shd[100*36];   // 14400 B
  __shared__ __align__(16) unsigned shcw[4096];    // 16384 B: CWC2 all classes
  __shared__ unsigned short scls[100];
  __shared__ float spart[3*192];                   // splits 1..3 partials
  const unsigned* wsu = (const unsigned*)ws;
  int blk = blockIdx.x;                            // 0..4095
  int xcd = blk & 7, local = blk >> 3;             // XCD-banded for L2 locality
  int ty0 = (xcd*8 + (local >> 6)) * 8;
  int tx0 = (local & 63) * 8;
  int t = threadIdx.x;
  int q = t & 1;                                   // channel-half (32 ch each)
  const uint4* F2 = (const uint4*)(wsu + O_FEAT);

  // stage CWC2 (16 KB) into LDS, coalesced
  {
    uint4* dst = (uint4*)shcw;
    const uint4* src = (const uint4*)(wsu + O_CWC2);
    #pragma unroll
    for (int k = 0; k < 4; k++) dst[t + k*256] = src[t + k*256];
  }
  __syncthreads();

  int s = t >> 1;                                  // 200 lane-tasks, single pass
  if (s < 100) {
    int cls = 0;
    #pragma unroll
    for (int i = 1; i < 16; i++) cls += (s >= PREF3[i]) ? 1 : 0;
    int j = s - PREF3[cls];
    int a = cls >> 2, bb = cls & 3;
    int nx = ((bb == 0) | (bb == 3)) ? 3 : 2;
    int jy = (nx == 3) ? ((j*11) >> 5) : (j >> 1);
    int jx = j - jy*nx;
    int py = ((a + 1) & 3) + 4*jy;
    int px = ((bb + 1) & 3) + 4*jx;
    int pos = py*10 + px;
    unsigned* row = &shd[pos*36 + q*16];
    int gy = ty0 - 1 + py, gx = tx0 - 1 + px;
    if ((gy < 0) | (gy >= HS) | (gx < 0) | (gx >= WSZ)) {
      if (q == 0) scls[pos] = 0;
      ((uint4*)row)[0] = make_uint4(0,0,0,0);
      ((uint4*)row)[1] = make_uint4(0,0,0,0);
      ((uint4*)row)[2] = make_uint4(0,0,0,0);
      ((uint4*)row)[3] = make_uint4(0,0,0,0);
      shd[pos*36 + 32 + q*2 + 0] = 0u;
      shd[pos*36 + 32 + q*2 + 1] = 0u;
    } else {
      if (q == 0) scls[pos] = (unsigned short)cls;
      float off0 = ws[O_OFFTAB + cls*2 + 0];
      float off1 = ws[O_OFFTAB + cls*2 + 1];
      float gxf = (((float)gx + 0.5f)*0.25f - 0.5f)*(2.0f/127.0f) - 1.0f + off0*(2.0f/127.0f);
      float gyf = (((float)gy + 0.5f)*0.25f - 0.5f)*(2.0f/127.0f) - 1.0f + off1*(2.0f/127.0f);
      float sx = (gxf + 1.0f)*0.5f*127.0f;
      float sy = (gyf + 1.0f)*0.5f*127.0f;
      float x0f = floorf(sx), y0f = floorf(sy);
      float fx = sx - x0f, fy = sy - y0f;
      int ix0 = (int)x0f, iy0 = (int)y0f;
      int ix1 = ix0 + 1, iy1 = iy0 + 1;
      float wx0 = 1.0f - fx, wy0 = 1.0f - fy;
      float w00 = wy0*wx0, w01 = wy0*fx, w10 = fy*wx0, w11 = fy*fx;
      bool vx0 = (ix0 >= 0) & (ix0 < WW), vx1 = (ix1 >= 0) & (ix1 < WW);
      bool vy0 = (iy0 >= 0) & (iy0 < HH), vy1 = (iy1 >= 0) & (iy1 < HH);
      if (!(vy0 & vx0)) w00 = 0.0f;
      if (!(vy0 & vx1)) w01 = 0.0f;
      if (!(vy1 & vx0)) w10 = 0.0f;
      if (!(vy1 & vx1)) w11 = 0.0f;
      int cx0 = min(max(ix0, 0), WW-1), cx1 = min(max(ix1, 0), WW-1);
      int cy0 = min(max(iy0, 0), HH-1), cy1 = min(max(iy1, 0), HH-1);
      int b00 = (cy0*WW + cx0)*8 + q*4, b01 = (cy0*WW + cx1)*8 + q*4;
      int b10 = (cy1*WW + cx0)*8 + q*4, b11 = (cy1*WW + cx1)*8 + q*4;

      // batch all 16 tap loads (forced wide load window)
      uint4 A0 = F2[b00+0], A1 = F2[b00+1], A2 = F2[b00+2], A3 = F2[b00+3];
      uint4 B0 = F2[b01+0], B1 = F2[b01+1], B2 = F2[b01+2], B3 = F2[b01+3];
      uint4 C0 = F2[b10+0], C1 = F2[b10+1], C2 = F2[b10+2], C3 = F2[b10+3];
      uint4 D0 = F2[b11+0], D1 = F2[b11+1], D2 = F2[b11+2], D3 = F2[b11+3];

      h2 W00 = { (__fp16)w00, (__fp16)w00 };
      h2 W01 = { (__fp16)w01, (__fp16)w01 };
      h2 W10 = { (__fp16)w10, (__fp16)w10 };
      h2 W11 = { (__fp16)w11, (__fp16)w11 };

      unsigned fp[16];
      fp[ 0] = blend4(A0.x,B0.x,C0.x,D0.x,W00,W01,W10,W11);
      fp[ 1] = blend4(A0.y,B0.y,C0.y,D0.y,W00,W01,W10,W11);
      fp[ 2] = blend4(A0.z,B0.z,C0.z,D0.z,W00,W01,W10,W11);
      fp[ 3] = blend4(A0.w,B0.w,C0.w,D0.w,W00,W01,W10,W11);
      fp[ 4] = blend4(A1.x,B1.x,C1.x,D1.x,W00,W01,W10,W11);
      fp[ 5] = blend4(A1.y,B1.y,C1.y,D1.y,W00,W01,W10,W11);
      fp[ 6] = blend4(A1.z,B1.z,C1.z,D1.z,W00,W01,W10,W11);
      fp[ 7] = blend4(A1.w,B1.w,C1.w,D1.w,W00,W01,W10,W11);
      fp[ 8] = blend4(A2.x,B2.x,C2.x,D2.x,W00,W01,W10,W11);
      fp[ 9] = blend4(A2.y,B2.y,C2.y,D2.y,W00,W01,W10,W11);
      fp[10] = blend4(A2.z,B2.z,C2.z,D2.z,W00,W01,W10,W11);
      fp[11] = blend4(A2.w,B2.w,C2.w,D2.w,W00,W01,W10,W11);
      fp[12] = blend4(A3.x,B3.x,C3.x,D3.x,W00,W01,W10,W11);
      fp[13] = blend4(A3.y,B3.y,C3.y,D3.y,W00,W01,W10,W11);
      fp[14] = blend4(A3.z,B3.z,C3.z,D3.z,W00,W01,W10,W11);
      fp[15] = blend4(A3.w,B3.w,C3.w,D3.w,W00,W01,W10,W11);

      ((uint4*)row)[0] = make_uint4(fp[0],  fp[1],  fp[2],  fp[3]);
      ((uint4*)row)[1] = make_uint4(fp[4],  fp[5],  fp[6],  fp[7]);
      ((uint4*)row)[2] = make_uint4(fp[8],  fp[9],  fp[10], fp[11]);
      ((uint4*)row)[3] = make_uint4(fp[12], fp[13], fp[14], fp[15]);

      // mid from LDS-staged CWC2 (broadcast within class runs)
      const uint4* CWv = (const uint4*)&shcw[cls*256] + q*32;
      float mid[8] = {0,0,0,0,0,0,0,0};
      #pragma unroll
      for (int i = 0; i < 16; i++) {
        uint4 w0 = CWv[i*2], w1 = CWv[i*2+1];
        h2 f = uh(fp[i]);
        mid[0] = FDOT2(f, uh(w0.x), mid[0]); mid[1] = FDOT2(f, uh(w0.y), mid[1]);
        mid[2] = FDOT2(f, uh(w0.z), mid[2]); mid[3] = FDOT2(f, uh(w0.w), mid[3]);
        mid[4] = FDOT2(f, uh(w1.x), mid[4]); mid[5] = FDOT2(f, uh(w1.y), mid[5]);
        mid[6] = FDOT2(f, uh(w1.z), mid[6]); mid[7] = FDOT2(f, uh(w1.w), mid[7]);
      }
      #pragma unroll
      for (int k = 0; k < 8; k++) mid[k] += __shfl_xor(mid[k], 1);
      shd[pos*36 + 32 + q*2 + 0] = pkh(mid[q*4+0], mid[q*4+1]);
      shd[pos*36 + 32 + q*2 + 1] = pkh(mid[q*4+2], mid[q*4+3]);
    }
  }
  __syncthreads();

  // ---- tail: wave-uniform 4-way split (split = wave idx) ----
  int split = t >> 6, pi = t & 63;
  int tx = pi & 7, ty = pi >> 3;
  const unsigned* TW2 = wsu + O_TW2;
  float a0, a1, a2;
  if (split == 0) { a0 = ws[O_TB+0]; a1 = ws[O_TB+1]; a2 = ws[O_TB+2]; }
  else            { a0 = 0.0f; a1 = 0.0f; a2 = 0.0f; }
  const int JB[4] = {0, 2, 5, 7};
  const int JE[4] = {2, 5, 7, 9};
  #pragma unroll
  for (int j = 0; j < 9; j++) {
    int dy = j / 3, dx = j - dy*3;
    int pp = (ty + dy)*10 + (tx + dx);
    const uint4* frow = (const uint4*)&shd[pp*36 + split*8];
    uint4 f0 = frow[0], f1 = frow[1];
    int cb = split*8;
    a0 = FDOT2(uh(f0.x), uh(TW2[(0*9+j)*32 + cb+0]), a0);
    a0 = FDOT2(uh(f0.y), uh(TW2[(0*9+j)*32 + cb+1]), a0);
    a0 = FDOT2(uh(f0.z), uh(TW2[(0*9+j)*32 + cb+2]), a0);
    a0 = FDOT2(uh(f0.w), uh(TW2[(0*9+j)*32 + cb+3]), a0);
    a0 = FDOT2(uh(f1.x), uh(TW2[(0*9+j)*32 + cb+4]), a0);
    a0 = FDOT2(uh(f1.y), uh(TW2[(0*9+j)*32 + cb+5]), a0);
    a0 = FDOT2(uh(f1.z), uh(TW2[(0*9+j)*32 + cb+6]), a0);
    a0 = FDOT2(uh(f1.w), uh(TW2[(0*9+j)*32 + cb+7]), a0);
    a1 = FDOT2(uh(f0.x), uh(TW2[(1*9+j)*32 + cb+0]), a1);
    a1 = FDOT2(uh(f0.y), uh(TW2[(1*9+j)*32 + cb+1]), a1);
    a1 = FDOT2(uh(f0.z), uh(TW2[(1*9+j)*32 + cb+2]), a1);
    a1 = FDOT2(uh(f0.w), uh(TW2[(1*9+j)*32 + cb+3]), a1);
    a1 = FDOT2(uh(f1.x), uh(TW2[(1*9+j)*32 + cb+4]), a1);
    a1 = FDOT2(uh(f1.y), uh(TW2[(1*9+j)*32 + cb+5]), a1);
    a1 = FDOT2(uh(f1.z), uh(TW2[(1*9+j)*32 + cb+6]), a1);
    a1 = FDOT2(uh(f1.w), uh(TW2[(1*9+j)*32 + cb+7]), a1);
    a2 = FDOT2(uh(f0.x), uh(TW2[(2*9+j)*32 + cb+0]), a2);
    a2 = FDOT2(uh(f0.y), uh(TW2[(2*9+j)*32 + cb+1]), a2);
    a2 = FDOT2(uh(f0.z), uh(TW2[(2*9+j)*32 + cb+2]), a2);
    a2 = FDOT2(uh(f0.w), uh(TW2[(2*9+j)*32 + cb+3]), a2);
    a2 = FDOT2(uh(f1.x), uh(TW2[(2*9+j)*32 + cb+4]), a2);
    a2 = FDOT2(uh(f1.y), uh(TW2[(2*9+j)*32 + cb+5]), a2);
    a2 = FDOT2(uh(f1.z), uh(TW2[(2*9+j)*32 + cb+6]), a2);
    a2 = FDOT2(uh(f1.w), uh(TW2[(2*9+j)*32 + cb+7]), a2);
    if (j >= JB[split] && j < JE[split]) {
      int cl = scls[pp];
      uint4 mv = *(const uint4*)&shd[pp*36 + 32];
      const uint4* Wp = (const uint4*)(wsu + O_W2P) + (cl*9 + j)*3;
      uint4 w0 = Wp[0], w1 = Wp[1], w2 = Wp[2];
      h2 m0 = uh(mv.x), m1 = uh(mv.y), m2 = uh(mv.z), m3 = uh(mv.w);
      a0 = FDOT2(m0, uh(w0.x), a0); a0 = FDOT2(m1, uh(w0.y), a0);
      a0 = FDOT2(m2, uh(w0.z), a0); a0 = FDOT2(m3, uh(w0.w), a0);
      a1 = FDOT2(m0, uh(w1.x), a1); a1 = FDOT2(m1, uh(w1.y), a1);
      a1 = FDOT2(m2, uh(w1.z), a1); a1 = FDOT2(m3, uh(w1.w), a1);
      a2 = FDOT2(m0, uh(w2.x), a2); a2 = FDOT2(m1, uh(w2.y), a2);
      a2 = FDOT2(m2, uh(w2.z), a2); a2 = FDOT2(m3, uh(w2.w), a2);
    }
  }
  if (split != 0) {
    float* sp = spart + (split-1)*192 + pi*3;
    sp[0] = a0; sp[1] = a1; sp[2] = a2;
  }
  __syncthreads();
  if (split == 0) {
    #pragma unroll
    for (int k = 0; k < 3; k++) {
      const float* sp = spart + k*192 + pi*3;
      a0 += sp[0]; a1 += sp[1]; a2 += sp[2];
    }
    ((uint2*)pred4)[blk*64 + pi] = make_uint2(pkbf(a0, a1), pkbf(a2, 0.0f));
  }
}

// ==== K3: query gather ====
__global__ __launch_bounds__(256) void k_gather(const void* __restrict__ inp,
                                                const void* __restrict__ coord, const void* __restrict__ cell,
                                                const float* __restrict__ ws, void* __restrict__ outp) {
  bool f32m = sniff_f32(inp);
  const uint2* pred4 = (const uint2*)((const unsigned*)ws + O_PRED);
  int q = blockIdx.x*256 + threadIdx.x;
  float cy, cx, ly, lx;
  if (f32m) {
    float2 c = ((const float2*)coord)[q]; cy = c.x; cx = c.y;
    float2 l = ((const float2*)cell)[q];  ly = l.x; lx = l.y;
  } else {
    unsigned cu = ((const unsigned*)coord)[q]; cy = asf(cu<<16); cx = asf(cu & 0xffff0000u);
    unsigned lu = ((const unsigned*)cell)[q];  ly = asf(lu<<16); lx = asf(lu & 0xffff0000u);
  }
  float gyq = fminf(fmaxf(cy - ly*0.5f + 1e-6f, -1.0f + 1e-6f), 1.0f - 1e-6f);
  float gxq = fminf(fmaxf(cx - lx*0.5f + 1e-6f, -1.0f + 1e-6f), 1.0f - 1e-6f);
  int xi = (int)rintf((gxq + 1.0f)*0.5f*511.0f);
  int yi = (int)rintf((gyq + 1.0f)*0.5f*511.0f);
  xi = min(max(xi, 0), WSZ-1);
  yi = min(max(yi, 0), HS-1);
  int row = yi >> 3, col = xi >> 3;
  int xcd = row >> 3;
  int local = (row & 7)*64 + col;
  int blk = local*8 + xcd;
  int pi = (yi & 7)*8 + (xi & 7);
  uint2 d = pred4[blk*64 + pi];
  float v0 = asf(d.x << 16), v1 = asf(d.x & 0xffff0000u), v2 = asf(d.y << 16);
  if (f32m) {
    float* o = (float*)outp;
    o[q*3 + 0] = v0; o[q*3 + 1] = v1; o[q*3 + 2] = v2;
  } else {
    bf16* o = (bf16*)outp;
    o[q*3 + 0] = __float2bfloat16(v0);
    o[q*3 + 1] = __float2bfloat16(v1);
    o[q*3 + 2] = __float2bfloat16(v2);
  }
}

extern "C" void kernel_launch(void* const* d_in, const int* in_sizes, int n_in,
                              void* d_out, int out_size, void* d_ws, size_t ws_size,
                              hipStream_t stream) {
  const void* inp   = d_in[0];
  const void* coord = d_in[1];
  const void* cell  = d_in[2];
  const void* encw  = d_in[3];
  const void* encb  = d_in[4];
  const void* w1    = d_in[5];
  const void* b1    = d_in[6];
  const void* w2    = d_in[7];
  const void* b2    = d_in[8];
  const void* rw    = d_in[9];
  const void* rb    = d_in[10];
  const void* ow    = d_in[11];
  const void* ob    = d_in[12];
  const void* tw    = d_in[13];
  const void* tb    = d_in[14];
  const void* wc    = d_in[15];
  const void* we    = d_in[16];

  float* wsf = (float*)d_ws;
  unsigned* pred4 = (unsigned*)wsf + O_PRED;

  k_prep<<<273, 256, 0, stream>>>(inp, encw, encb, w1, b1, w2, b2, rw, rb, ow, ob, tw, tb, wc, we, wsf);
  k_maintail<<<4096, 256, 0, stream>>>(wsf, pred4);
  k_gather<<<1024, 256, 0, stream>>>(inp, coord, cell, wsf, d_out);
}

// Round 13
// 160.123 us; speedup vs baseline: 1.1440x; 1.0328x over previous
//
#include <hip/hip_runtime.h>
#include <hip/hip_bf16.h>

typedef __hip_bfloat16 bf16;
typedef __fp16 h2 __attribute__((ext_vector_type(2)));   // matches V2h of amdgcn builtins

__device__ __forceinline__ float bf2f(bf16 h) { return __bfloat162float(h); }
__device__ __forceinline__ bf16 us2bf(unsigned short u){ union{unsigned short s; bf16 h;}v; v.s=u; return v.h; }
__device__ __forceinline__ float asf(unsigned u){ union{unsigned u; float f;}v; v.u=u; return v.f; }
__device__ __forceinline__ h2 uh(unsigned u){ union{unsigned u; h2 h;}v; v.u=u; return v.h; }
__device__ __forceinline__ unsigned pkh(float a, float b){ union{h2 h; unsigned u;}v; v.h=__builtin_amdgcn_cvt_pkrtz(a,b); return v.u; }
__device__ __forceinline__ unsigned short f2bu(float a){ union{bf16 h; unsigned short u;}v; v.h=__float2bfloat16(a); return v.u; }
__device__ __forceinline__ unsigned pkbf(float a, float b){ return ((unsigned)f2bu(b) << 16) | (unsigned)f2bu(a); }
#define FDOT2(va,vb,acc) __builtin_amdgcn_fdot2((va),(vb),(acc),false)

#define HH 128
#define WW 128
#define HS 512
#define WSZ 512

// ---- ws dword-offset layout ----
#define O_OFFTAB 0        // 32 f32
#define O_TB     32       // 3 f32
#define O_TW2    64       // 864 u32: tail weights f16 pairs [o][j][cpair]
#define O_CWC2   1024     // 4096 u32: f16 pairs [cls][cp][k]
#define O_W2P    5120     // 1728 u32: f16 pairs [cls][j][o][kpair]
#define O_FEAT   8192     // 524288 u32: feat packed f16 pairs, HWC [px][cp]
#define O_PRED   1056768  // 524288 u32: bf16x4-packed pred, block-sorted [blk][pi]

// k_prep LDS pool carve (f32 units)
#define SH_W2T 0          // 64*65 transposed w2
#define SH_WE  4160       // 2048
#define SH_WC  6208       // 2048
#define SH_TW  8256       // 1728
#define SH_OW  9984       // 128
#define SH_RW  10112      // 256
#define SH_END 10368

// class-sorted halo decode prefix for 10x18 halo (classes by ((p+3)&3))
__constant__ int PREF2[16] = {0,15,27,39,54,64,72,80,90,100,108,116,126,141,153,165};

__device__ __forceinline__ float rdin(const void* p, int i, bool f32m) {
  return f32m ? ((const float*)p)[i] : bf2f(((const bf16*)p)[i]);
}
__device__ __forceinline__ float rdw(const void* p, int i, bool f32m) {
  if (f32m) return ((const float*)p)[i];
  unsigned u = ((const unsigned*)p)[i>>1];
  return asf((i&1) ? (u & 0xffff0000u) : (u<<16));
}
__device__ __forceinline__ bool sniff_f32(const void* inp) {
  int lane = threadIdx.x & 63;
  unsigned short u = ((const unsigned short*)inp)[2*lane];
  float v = bf2f(us2bf(u));
  bool ok = (v == v) && (fabsf(v) < 64.0f);
  return __popcll(__ballot(ok)) < 48;
}
__device__ __forceinline__ unsigned blend4(unsigned a, unsigned b, unsigned c, unsigned d,
                                           h2 W00, h2 W01, h2 W10, h2 W11) {
  h2 f = uh(a)*W00 + uh(b)*W01 + uh(c)*W10 + uh(d)*W11;   // v_pk_fma_f16
  union{h2 h; unsigned u;} v; v.h = f; return v.u;
}

// ==== K1: encoder conv (f16-packed feat) + per-class MLP/weights (LDS-staged) ====
__global__ __launch_bounds__(256) void k_prep(
    const void* __restrict__ inp, const void* __restrict__ encw, const void* __restrict__ encb,
    const void* __restrict__ w1, const void* __restrict__ b1,
    const void* __restrict__ w2, const void* __restrict__ b2,
    const void* __restrict__ rw, const void* __restrict__ rb,
    const void* __restrict__ ow, const void* __restrict__ ob,
    const void* __restrict__ tw, const void* __restrict__ tb,
    const void* __restrict__ wc, const void* __restrict__ we,
    float* __restrict__ ws) {
  __shared__ float shpool[SH_END];
  __shared__ float sh1[64];
  __shared__ float sh2[64];
  __shared__ float shr[4];
  __shared__ float shcwe[512];
  bool f32m = sniff_f32(inp);
  int b = blockIdx.x, t = threadIdx.x;
  unsigned* wsu = (unsigned*)ws;

  if (b < 256) {
    // ---- encoder conv 3->64: block = (channel-group g, 256-px tile) ----
    int g = b >> 6;                 // oc [g*16, g*16+16)
    int px = (b & 63)*256 + t;
    float* shw = shpool;            // 432
    float* shb = shpool + 432;      // 16
    for (int i = t; i < 432; i += 256) shw[i] = rdw(encw, g*432 + i, f32m);
    if (t < 16) shb[t] = rdw(encb, g*16 + t, f32m);
    __syncthreads();
    int x = px & 127, y = px >> 7;
    float tp[27];
    #pragma unroll
    for (int ic = 0; ic < 3; ic++)
      #pragma unroll
      for (int dy = 0; dy < 3; dy++) {
        int yy = y + dy - 1;
        #pragma unroll
        for (int dx = 0; dx < 3; dx++) {
          int xx = x + dx - 1;
          bool ok = (yy >= 0) & (yy < 128) & (xx >= 0) & (xx < 128);
          tp[ic*9 + dy*3 + dx] = ok ? rdin(inp, ic*16384 + yy*128 + xx, f32m) : 0.0f;
        }
      }
    unsigned e[8];
    #pragma unroll
    for (int o4 = 0; o4 < 4; o4++) {
      float a[4];
      #pragma unroll
      for (int oo = 0; oo < 4; oo++) {
        int o2 = o4*4 + oo;
        float acc = shb[o2];
        #pragma unroll
        for (int kk = 0; kk < 27; kk++) acc = fmaf(shw[o2*27 + kk], tp[kk], acc);
        a[oo] = acc;
      }
      e[o4*2]   = pkh(a[0], a[1]);
      e[o4*2+1] = pkh(a[2], a[3]);
    }
    uint4* outp = (uint4*)(wsu + O_FEAT + px*32 + g*8);
    outp[0] = make_uint4(e[0], e[1], e[2], e[3]);
    outp[1] = make_uint4(e[4], e[5], e[6], e[7]);
  } else if (b < 272) {
    // ---- per-class MLP -> off, r; fold into CWC2 / W2P (weights LDS-staged) ----
    int cls = b - 256;
    for (int i = t; i < 4096; i += 256) shpool[SH_W2T + (i & 63)*65 + (i >> 6)] = rdw(w2, i, f32m);
    for (int i = t; i < 2048; i += 256) { shpool[SH_WE + i] = rdw(we, i, f32m); shpool[SH_WC + i] = rdw(wc, i, f32m); }
    for (int i = t; i < 1728; i += 256) shpool[SH_TW + i] = rdw(tw, i, f32m);
    for (int i = t; i < 128; i += 256)  shpool[SH_OW + i] = rdw(ow, i, f32m);
    for (int i = t; i < 256; i += 256)  shpool[SH_RW + i] = rdw(rw, i, f32m);
    if (t < 64) {
      float mcls = (float)(cls >> 2), ncls = (float)(cls & 3);
      float chv = (mcls + 0.5f)*0.25f - 0.5f;
      float cwv = (ncls + 0.5f)*0.25f - 0.5f;
      float s1 = rdw(w1,t*4+0,f32m)*0.25f + rdw(w1,t*4+1,f32m)*0.25f
               + rdw(w1,t*4+2,f32m)*chv + rdw(w1,t*4+3,f32m)*cwv + rdw(b1,t,f32m);
      sh1[t] = fmaxf(s1, 0.0f);
    }
    __syncthreads();
    if (t < 64) {
      float s2 = rdw(b2,t,f32m);
      for (int i = 0; i < 64; i++) s2 = fmaf(shpool[SH_W2T + i*65 + t], sh1[i], s2);
      sh2[t] = fmaxf(s2, 0.0f);
    }
    __syncthreads();
    if (t < 2) {
      float a = rdw(ob,t,f32m);
      for (int i = 0; i < 64; i++) a = fmaf(shpool[SH_OW + t*64 + i], sh2[i], a);
      ws[O_OFFTAB + cls*2 + t] = a;
    } else if (t < 6) {
      int e = t - 2;
      float a = rdw(rb,e,f32m);
      for (int i = 0; i < 64; i++) a = fmaf(shpool[SH_RW + e*64 + i], sh2[i], a);
      shr[e] = 1.0f / (1.0f + expf(-a));
    }
    __syncthreads();
    float r0 = shr[0], r1 = shr[1], r2 = shr[2], r3 = shr[3];
    for (int idx = t; idx < 512; idx += 256) {
      float a =       r0 * shpool[SH_WE + idx];
      a = fmaf(r1, shpool[SH_WE +  512 + idx], a);
      a = fmaf(r2, shpool[SH_WE + 1024 + idx], a);
      a = fmaf(r3, shpool[SH_WE + 1536 + idx], a);
      shcwe[idx] = a;
    }
    unsigned* wcw = wsu + O_CWC2 + cls*256;
    for (int idx = t; idx < 256; idx += 256) {
      int cp = idx >> 3, k = idx & 7;
      float lo =       r0 * shpool[SH_WC +        k*64 + 2*cp];
      lo = fmaf(r1, shpool[SH_WC +  512 + k*64 + 2*cp], lo);
      lo = fmaf(r2, shpool[SH_WC + 1024 + k*64 + 2*cp], lo);
      lo = fmaf(r3, shpool[SH_WC + 1536 + k*64 + 2*cp], lo);
      float hi =       r0 * shpool[SH_WC +        k*64 + 2*cp + 1];
      hi = fmaf(r1, shpool[SH_WC +  512 + k*64 + 2*cp + 1], hi);
      hi = fmaf(r2, shpool[SH_WC + 1024 + k*64 + 2*cp + 1], hi);
      hi = fmaf(r3, shpool[SH_WC + 1536 + k*64 + 2*cp + 1], hi);
      wcw[idx] = pkh(lo, hi);
    }
    __syncthreads();
    unsigned* wpp = wsu + O_W2P;
    for (int idx = t; idx < 108; idx += 256) {
      int j = idx / 12, rem = idx - j*12, o2 = rem >> 2, kp = rem & 3;
      float alo = 0.0f, ahi = 0.0f;
      for (int c = 0; c < 64; c++) {
        float tv = shpool[SH_TW + (o2*64 + c)*9 + j];
        alo = fmaf(tv, shcwe[c*8 + 2*kp],     alo);
        ahi = fmaf(tv, shcwe[c*8 + 2*kp + 1], ahi);
      }
      wpp[(cls*9 + j)*12 + o2*4 + kp] = pkh(alo, ahi);
    }
  } else {
    for (int idx = t; idx < 864; idx += 256) {
      int o2 = idx / 288, rem = idx - o2*288, j = rem >> 5, cp = rem & 31;
      unsigned d = pkh(rdw(tw, (o2*64 + 2*cp    )*9 + j, f32m),
                       rdw(tw, (o2*64 + 2*cp + 1)*9 + j, f32m));
      (wsu + O_TW2)[idx] = d;
    }
    if (t < 3) ws[O_TB + t] = rdin(tb, t, f32m);
  }
}

// ==== K2: fused main+tail, tile 8x16, halo 10x18, CWC2 LDS (132-dw padded rows) ====
// shd row: dwords 0..31 = fc f16 pairs (64 ch), 32..35 = mid f16 pairs. stride 36 dw.
__global__ __launch_bounds__(256) void k_maintail(const float* __restrict__ ws, unsigned* __restrict__ pred4) {
  __shared__ __align__(16) unsigned shd[180*36];   // 25920 B
  __shared__ __align__(16) unsigned shcw[32*132];  // 16896 B: CWC2, combo=cls*2+q, 132-dw rows
  __shared__ unsigned short scls[180];
  __shared__ float spart[128*3];
  const unsigned* wsu = (const unsigned*)ws;
  int blk = blockIdx.x;                            // 0..2047
  int xcd = blk & 7, local = blk >> 3;             // XCD-banded for L2 locality
  int ty0 = (xcd*8 + (local >> 5)) * 8;
  int tx0 = (local & 31) * 16;
  int t = threadIdx.x;
  int q = t & 1;                                   // channel-half (32 ch each)
  const uint4* F2 = (const uint4*)(wsu + O_FEAT);

  // stage CWC2 (16 KB) into bank-padded LDS rows
  {
    const uint4* src = (const uint4*)(wsu + O_CWC2);
    #pragma unroll
    for (int k = 0; k < 4; k++) {
      int e = t + k*256;                 // 0..1023 uint4s
      int combo = e >> 5, idx = e & 31;
      ((uint4*)&shcw[combo*132])[idx] = src[e];
    }
  }
  __syncthreads();

  for (int s0 = 0; s0 < 256; s0 += 128) {
    int s = s0 + (t >> 1);
    if (s >= 180) continue;
    int cls = 0;
    #pragma unroll
    for (int i = 1; i < 16; i++) cls += (s >= PREF2[i]) ? 1 : 0;
    int j = s - PREF2[cls];
    int a = cls >> 2, bb = cls & 3;
    int nx = ((bb == 0) | (bb == 3)) ? 5 : 4;
    int jy = (nx == 4) ? (j >> 2) : ((j*13) >> 6);
    int jx = j - jy*nx;
    int py = ((a + 1) & 3) + 4*jy;
    int px = ((bb + 1) & 3) + 4*jx;
    int pos = py*18 + px;
    unsigned* row = &shd[pos*36 + q*16];
    int gy = ty0 - 1 + py, gx = tx0 - 1 + px;
    if ((gy < 0) | (gy >= HS) | (gx < 0) | (gx >= WSZ)) {
      if (q == 0) scls[pos] = 0;
      ((uint4*)row)[0] = make_uint4(0,0,0,0);
      ((uint4*)row)[1] = make_uint4(0,0,0,0);
      ((uint4*)row)[2] = make_uint4(0,0,0,0);
      ((uint4*)row)[3] = make_uint4(0,0,0,0);
      shd[pos*36 + 32 + q*2 + 0] = 0u;
      shd[pos*36 + 32 + q*2 + 1] = 0u;
      continue;
    }
    if (q == 0) scls[pos] = (unsigned short)cls;
    float off0 = ws[O_OFFTAB + cls*2 + 0];
    float off1 = ws[O_OFFTAB + cls*2 + 1];
    float gxf = (((float)gx + 0.5f)*0.25f - 0.5f)*(2.0f/127.0f) - 1.0f + off0*(2.0f/127.0f);
    float gyf = (((float)gy + 0.5f)*0.25f - 0.5f)*(2.0f/127.0f) - 1.0f + off1*(2.0f/127.0f);
    float sx = (gxf + 1.0f)*0.5f*127.0f;
    float sy = (gyf + 1.0f)*0.5f*127.0f;
    float x0f = floorf(sx), y0f = floorf(sy);
    float fx = sx - x0f, fy = sy - y0f;
    int ix0 = (int)x0f, iy0 = (int)y0f;
    int ix1 = ix0 + 1, iy1 = iy0 + 1;
    float wx0 = 1.0f - fx, wy0 = 1.0f - fy;
    float w00 = wy0*wx0, w01 = wy0*fx, w10 = fy*wx0, w11 = fy*fx;
    bool vx0 = (ix0 >= 0) & (ix0 < WW), vx1 = (ix1 >= 0) & (ix1 < WW);
    bool vy0 = (iy0 >= 0) & (iy0 < HH), vy1 = (iy1 >= 0) & (iy1 < HH);
    if (!(vy0 & vx0)) w00 = 0.0f;
    if (!(vy0 & vx1)) w01 = 0.0f;
    if (!(vy1 & vx0)) w10 = 0.0f;
    if (!(vy1 & vx1)) w11 = 0.0f;
    int cx0 = min(max(ix0, 0), WW-1), cx1 = min(max(ix1, 0), WW-1);
    int cy0 = min(max(iy0, 0), HH-1), cy1 = min(max(iy1, 0), HH-1);
    int b00 = (cy0*WW + cx0)*8 + q*4, b01 = (cy0*WW + cx1)*8 + q*4;
    int b10 = (cy1*WW + cx0)*8 + q*4, b11 = (cy1*WW + cx1)*8 + q*4;

    // batch all 16 tap loads (forced wide load window)
    uint4 A0 = F2[b00+0], A1 = F2[b00+1], A2 = F2[b00+2], A3 = F2[b00+3];
    uint4 B0 = F2[b01+0], B1 = F2[b01+1], B2 = F2[b01+2], B3 = F2[b01+3];
    uint4 C0 = F2[b10+0], C1 = F2[b10+1], C2 = F2[b10+2], C3 = F2[b10+3];
    uint4 D0 = F2[b11+0], D1 = F2[b11+1], D2 = F2[b11+2], D3 = F2[b11+3];

    h2 W00 = { (__fp16)w00, (__fp16)w00 };
    h2 W01 = { (__fp16)w01, (__fp16)w01 };
    h2 W10 = { (__fp16)w10, (__fp16)w10 };
    h2 W11 = { (__fp16)w11, (__fp16)w11 };

    unsigned fp[16];
    fp[ 0] = blend4(A0.x,B0.x,C0.x,D0.x,W00,W01,W10,W11);
    fp[ 1] = blend4(A0.y,B0.y,C0.y,D0.y,W00,W01,W10,W11);
    fp[ 2] = blend4(A0.z,B0.z,C0.z,D0.z,W00,W01,W10,W11);
    fp[ 3] = blend4(A0.w,B0.w,C0.w,D0.w,W00,W01,W10,W11);
    fp[ 4] = blend4(A1.x,B1.x,C1.x,D1.x,W00,W01,W10,W11);
    fp[ 5] = blend4(A1.y,B1.y,C1.y,D1.y,W00,W01,W10,W11);
    fp[ 6] = blend4(A1.z,B1.z,C1.z,D1.z,W00,W01,W10,W11);
    fp[ 7] = blend4(A1.w,B1.w,C1.w,D1.w,W00,W01,W10,W11);
    fp[ 8] = blend4(A2.x,B2.x,C2.x,D2.x,W00,W01,W10,W11);
    fp[ 9] = blend4(A2.y,B2.y,C2.y,D2.y,W00,W01,W10,W11);
    fp[10] = blend4(A2.z,B2.z,C2.z,D2.z,W00,W01,W10,W11);
    fp[11] = blend4(A2.w,B2.w,C2.w,D2.w,W00,W01,W10,W11);
    fp[12] = blend4(A3.x,B3.x,C3.x,D3.x,W00,W01,W10,W11);
    fp[13] = blend4(A3.y,B3.y,C3.y,D3.y,W00,W01,W10,W11);
    fp[14] = blend4(A3.z,B3.z,C3.z,D3.z,W00,W01,W10,W11);
    fp[15] = blend4(A3.w,B3.w,C3.w,D3.w,W00,W01,W10,W11);

    ((uint4*)row)[0] = make_uint4(fp[0],  fp[1],  fp[2],  fp[3]);
    ((uint4*)row)[1] = make_uint4(fp[4],  fp[5],  fp[6],  fp[7]);
    ((uint4*)row)[2] = make_uint4(fp[8],  fp[9],  fp[10], fp[11]);
    ((uint4*)row)[3] = make_uint4(fp[12], fp[13], fp[14], fp[15]);

    // mid from bank-padded LDS CWC2
    const uint4* CWv = (const uint4*)&shcw[(cls*2 + q)*132];
    float mid[8] = {0,0,0,0,0,0,0,0};
    #pragma unroll
    for (int i = 0; i < 16; i++) {
      uint4 w0 = CWv[i*2], w1 = CWv[i*2+1];
      h2 f = uh(fp[i]);
      mid[0] = FDOT2(f, uh(w0.x), mid[0]); mid[1] = FDOT2(f, uh(w0.y), mid[1]);
      mid[2] = FDOT2(f, uh(w0.z), mid[2]); mid[3] = FDOT2(f, uh(w0.w), mid[3]);
      mid[4] = FDOT2(f, uh(w1.x), mid[4]); mid[5] = FDOT2(f, uh(w1.y), mid[5]);
      mid[6] = FDOT2(f, uh(w1.z), mid[6]); mid[7] = FDOT2(f, uh(w1.w), mid[7]);
    }
    #pragma unroll
    for (int k = 0; k < 8; k++) mid[k] += __shfl_xor(mid[k], 1);
    shd[pos*36 + 32 + q*2 + 0] = pkh(mid[q*4+0], mid[q*4+1]);
    shd[pos*36 + 32 + q*2 + 1] = pkh(mid[q*4+2], mid[q*4+3]);
  }
  __syncthreads();

  // ---- tail: 2-way wave-uniform split over channel halves; mid j-split ----
  int half = t >> 7, pi = t & 127;
  int tx = pi & 15, ty = pi >> 4;
  const unsigned* TW2 = wsu + O_TW2;
  float a0, a1, a2;
  if (half == 0) { a0 = ws[O_TB+0]; a1 = ws[O_TB+1]; a2 = ws[O_TB+2]; }
  else           { a0 = 0.0f; a1 = 0.0f; a2 = 0.0f; }
  int cb = half*16;
  #pragma unroll
  for (int j = 0; j < 9; j++) {
    int dy = j / 3, dx = j - dy*3;
    int pp = (ty + dy)*18 + (tx + dx);
    const uint4* frow = (const uint4*)&shd[pp*36 + half*16];
    uint4 f0 = frow[0], f1 = frow[1], f2 = frow[2], f3 = frow[3];
    const unsigned* T0 = TW2 + (0*9+j)*32 + cb;
    const unsigned* T1 = TW2 + (1*9+j)*32 + cb;
    const unsigned* T2 = TW2 + (2*9+j)*32 + cb;
    a0=FDOT2(uh(f0.x),uh(T0[0]),a0); a0=FDOT2(uh(f0.y),uh(T0[1]),a0); a0=FDOT2(uh(f0.z),uh(T0[2]),a0); a0=FDOT2(uh(f0.w),uh(T0[3]),a0);
    a0=FDOT2(uh(f1.x),uh(T0[4]),a0); a0=FDOT2(uh(f1.y),uh(T0[5]),a0); a0=FDOT2(uh(f1.z),uh(T0[6]),a0); a0=FDOT2(uh(f1.w),uh(T0[7]),a0);
    a0=FDOT2(uh(f2.x),uh(T0[8]),a0); a0=FDOT2(uh(f2.y),uh(T0[9]),a0); a0=FDOT2(uh(f2.z),uh(T0[10]),a0); a0=FDOT2(uh(f2.w),uh(T0[11]),a0);
    a0=FDOT2(uh(f3.x),uh(T0[12]),a0); a0=FDOT2(uh(f3.y),uh(T0[13]),a0); a0=FDOT2(uh(f3.z),uh(T0[14]),a0); a0=FDOT2(uh(f3.w),uh(T0[15]),a0);
    a1=FDOT2(uh(f0.x),uh(T1[0]),a1); a1=FDOT2(uh(f0.y),uh(T1[1]),a1); a1=FDOT2(uh(f0.z),uh(T1[2]),a1); a1=FDOT2(uh(f0.w),uh(T1[3]),a1);
    a1=FDOT2(uh(f1.x),uh(T1[4]),a1); a1=FDOT2(uh(f1.y),uh(T1[5]),a1); a1=FDOT2(uh(f1.z),uh(T1[6]),a1); a1=FDOT2(uh(f1.w),uh(T1[7]),a1);
    a1=FDOT2(uh(f2.x),uh(T1[8]),a1); a1=FDOT2(uh(f2.y),uh(T1[9]),a1); a1=FDOT2(uh(f2.z),uh(T1[10]),a1); a1=FDOT2(uh(f2.w),uh(T1[11]),a1);
    a1=FDOT2(uh(f3.x),uh(T1[12]),a1); a1=FDOT2(uh(f3.y),uh(T1[13]),a1); a1=FDOT2(uh(f3.z),uh(T1[14]),a1); a1=FDOT2(uh(f3.w),uh(T1[15]),a1);
    a2=FDOT2(uh(f0.x),uh(T2[0]),a2); a2=FDOT2(uh(f0.y),uh(T2[1]),a2); a2=FDOT2(uh(f0.z),uh(T2[2]),a2); a2=FDOT2(uh(f0.w),uh(T2[3]),a2);
    a2=FDOT2(uh(f1.x),uh(T2[4]),a2); a2=FDOT2(uh(f1.y),uh(T2[5]),a2); a2=FDOT2(uh(f1.z),uh(T2[6]),a2); a2=FDOT2(uh(f1.w),uh(T2[7]),a2);
    a2=FDOT2(uh(f2.x),uh(T2[8]),a2); a2=FDOT2(uh(f2.y),uh(T2[9]),a2); a2=FDOT2(uh(f2.z),uh(T2[10]),a2); a2=FDOT2(uh(f2.w),uh(T2[11]),a2);
    a2=FDOT2(uh(f3.x),uh(T2[12]),a2); a2=FDOT2(uh(f3.y),uh(T2[13]),a2); a2=FDOT2(uh(f3.z),uh(T2[14]),a2); a2=FDOT2(uh(f3.w),uh(T2[15]),a2);
    // mid part split by j: half0 j 0..4, half1 j 5..8
    bool mine = (half == 0) ? (j < 5) : (j >= 5);
    if (mine) {
      int cl = scls[pp];
      uint4 mv = *(const uint4*)&shd[pp*36 + 32];
      const uint4* Wp = (const uint4*)(wsu + O_W2P) + (cl*9 + j)*3;
      uint4 w0 = Wp[0], w1 = Wp[1], w2 = Wp[2];
      h2 m0 = uh(mv.x), m1 = uh(mv.y), m2 = uh(mv.z), m3 = uh(mv.w);
      a0 = FDOT2(m0, uh(w0.x), a0); a0 = FDOT2(m1, uh(w0.y), a0);
      a0 = FDOT2(m2, uh(w0.z), a0); a0 = FDOT2(m3, uh(w0.w), a0);
      a1 = FDOT2(m0, uh(w1.x), a1); a1 = FDOT2(m1, uh(w1.y), a1);
      a1 = FDOT2(m2, uh(w1.z), a1); a1 = FDOT2(m3, uh(w1.w), a1);
      a2 = FDOT2(m0, uh(w2.x), a2); a2 = FDOT2(m1, uh(w2.y), a2);
      a2 = FDOT2(m2, uh(w2.z), a2); a2 = FDOT2(m3, uh(w2.w), a2);
    }
  }
  if (half == 1) {
    spart[pi*3+0] = a0; spart[pi*3+1] = a1; spart[pi*3+2] = a2;
  }
  __syncthreads();
  if (half == 0) {
    a0 += spart[pi*3+0]; a1 += spart[pi*3+1]; a2 += spart[pi*3+2];
    ((uint2*)pred4)[blk*128 + pi] = make_uint2(pkbf(a0, a1), pkbf(a2, 0.0f));
  }
}

// ==== K3: query gather ====
__global__ __launch_bounds__(256) void k_gather(const void* __restrict__ inp,
                                                const void* __restrict__ coord, const void* __restrict__ cell,
                                                const float* __restrict__ ws, void* __restrict__ outp) {
  bool f32m = sniff_f32(inp);
  const uint2* pred4 = (const uint2*)((const unsigned*)ws + O_PRED);
  int q = blockIdx.x*256 + threadIdx.x;
  float cy, cx, ly, lx;
  if (f32m) {
    float2 c = ((const float2*)coord)[q]; cy = c.x; cx = c.y;
    float2 l = ((const float2*)cell)[q];  ly = l.x; lx = l.y;
  } else {
    unsigned cu = ((const unsigned*)coord)[q]; cy = asf(cu<<16); cx = asf(cu & 0xffff0000u);
    unsigned lu = ((const unsigned*)cell)[q];  ly = asf(lu<<16); lx = asf(lu & 0xffff0000u);
  }
  float gyq = fminf(fmaxf(cy - ly*0.5f + 1e-6f, -1.0f + 1e-6f), 1.0f - 1e-6f);
  float gxq = fminf(fmaxf(cx - lx*0.5f + 1e-6f, -1.0f + 1e-6f), 1.0f - 1e-6f);
  int xi = (int)rintf((gxq + 1.0f)*0.5f*511.0f);
  int yi = (int)rintf((gyq + 1.0f)*0.5f*511.0f);
  xi = min(max(xi, 0), WSZ-1);
  yi = min(max(yi, 0), HS-1);
  // invert 8x16 block-sorted layout (row-major pixels within tile)
  int row = yi >> 3, col = xi >> 4;
  int xcd = row >> 3;
  int local = (row & 7)*32 + col;
  int blk = local*8 + xcd;
  int pi = (yi & 7)*16 + (xi & 15);
  uint2 d = pred4[blk*128 + pi];
  float v0 = asf(d.x << 16), v1 = asf(d.x & 0xffff0000u), v2 = asf(d.y << 16);
  if (f32m) {
    float* o = (float*)outp;
    o[q*3 + 0] = v0; o[q*3 + 1] = v1; o[q*3 + 2] = v2;
  } else {
    bf16* o = (bf16*)outp;
    o[q*3 + 0] = __float2bfloat16(v0);
    o[q*3 + 1] = __float2bfloat16(v1);
    o[q*3 + 2] = __float2bfloat16(v2);
  }
}

extern "C" void kernel_launch(void* const* d_in, const int* in_sizes, int n_in,
                              void* d_out, int out_size, void* d_ws, size_t ws_size,
                              hipStream_t stream) {
  const void* inp   = d_in[0];
  const void* coord = d_in[1];
  const void* cell  = d_in[2];
  const void* encw  = d_in[3];
  const void* encb  = d_in[4];
  const void* w1    = d_in[5];
  const void* b1    = d_in[6];
  const void* w2    = d_in[7];
  const void* b2    = d_in[8];
  const void* rw    = d_in[9];
  const void* rb    = d_in[10];
  const void* ow    = d_in[11];
  const void* ob    = d_in[12];
  const void* tw    = d_in[13];
  const void* tb    = d_in[14];
  const void* wc    = d_in[15];
  const void* we    = d_in[16];

  float* wsf = (float*)d_ws;
  unsigned* pred4 = (unsigned*)wsf + O_PRED;

  k_prep<<<273, 256, 0, stream>>>(inp, encw, encb, w1, b1, w2, b2, rw, rb, ow, ob, tw, tb, wc, we, wsf);
  k_maintail<<<2048, 256, 0, stream>>>(wsf, pred4);
  k_gather<<<1024, 256, 0, stream>>>(inp, coord, cell, wsf, d_out);
}

// Round 14
// 154.353 us; speedup vs baseline: 1.1868x; 1.0374x over previous
//
#include <hip/hip_runtime.h>
#include <hip/hip_bf16.h>

typedef __hip_bfloat16 bf16;
typedef __fp16 h2 __attribute__((ext_vector_type(2)));   // matches V2h of amdgcn builtins

__device__ __forceinline__ float bf2f(bf16 h) { return __bfloat162float(h); }
__device__ __forceinline__ bf16 us2bf(unsigned short u){ union{unsigned short s; bf16 h;}v; v.s=u; return v.h; }
__device__ __forceinline__ float asf(unsigned u){ union{unsigned u; float f;}v; v.u=u; return v.f; }
__device__ __forceinline__ h2 uh(unsigned u){ union{unsigned u; h2 h;}v; v.u=u; return v.h; }
__device__ __forceinline__ unsigned pkh(float a, float b){ union{h2 h; unsigned u;}v; v.h=__builtin_amdgcn_cvt_pkrtz(a,b); return v.u; }
__device__ __forceinline__ unsigned short f2bu(float a){ union{bf16 h; unsigned short u;}v; v.h=__float2bfloat16(a); return v.u; }
__device__ __forceinline__ unsigned pkbf(float a, float b){ return ((unsigned)f2bu(b) << 16) | (unsigned)f2bu(a); }
#define FDOT2(va,vb,acc) __builtin_amdgcn_fdot2((va),(vb),(acc),false)

#define HH 128
#define WW 128
#define HS 512
#define WSZ 512

// ---- ws dword-offset layout ----
#define O_OFFTAB 0        // 32 f32
#define O_TB     32       // 3 f32
#define O_TW2    64       // 864 u32: tail weights f16 pairs [o][j][cpair]
#define O_CWC2   1024     // 4096 u32: f16 pairs [cls][cp][k]
#define O_W2P    5120     // 1728 u32: f16 pairs [cls][j][o][kpair]
#define O_FEAT   8192     // 524288 u32: feat packed f16 pairs, HWC [px][cp]
#define O_PRED   1056768  // 524288 u32: bf16x4-packed pred, block-sorted [blk][pi]

// k_prep LDS pool carve (f32 units)
#define SH_W2T 0          // 64*65 transposed w2
#define SH_WE  4160       // 2048
#define SH_WC  6208       // 2048
#define SH_TW  8256       // 1728
#define SH_OW  9984       // 128
#define SH_RW  10112      // 256
#define SH_END 10368

// class-sorted halo decode prefix for 10x18 halo (classes by ((p+3)&3))
__constant__ int PREF2[16] = {0,15,27,39,54,64,72,80,90,100,108,116,126,141,153,165};

__device__ __forceinline__ float rdin(const void* p, int i, bool f32m) {
  return f32m ? ((const float*)p)[i] : bf2f(((const bf16*)p)[i]);
}
__device__ __forceinline__ float rdw(const void* p, int i, bool f32m) {
  if (f32m) return ((const float*)p)[i];
  unsigned u = ((const unsigned*)p)[i>>1];
  return asf((i&1) ? (u & 0xffff0000u) : (u<<16));
}
__device__ __forceinline__ bool sniff_f32(const void* inp) {
  int lane = threadIdx.x & 63;
  unsigned short u = ((const unsigned short*)inp)[2*lane];
  float v = bf2f(us2bf(u));
  bool ok = (v == v) && (fabsf(v) < 64.0f);
  return __popcll(__ballot(ok)) < 48;
}
__device__ __forceinline__ unsigned blend4(unsigned a, unsigned b, unsigned c, unsigned d,
                                           h2 W00, h2 W01, h2 W10, h2 W11) {
  h2 f = uh(a)*W00 + uh(b)*W01 + uh(c)*W10 + uh(d)*W11;   // v_pk_fma_f16
  union{h2 h; unsigned u;} v; v.h = f; return v.u;
}

// ==== K1: encoder conv (f16-packed feat) + per-class MLP/weights (LDS-staged) ====
__global__ __launch_bounds__(256) void k_prep(
    const void* __restrict__ inp, const void* __restrict__ encw, const void* __restrict__ encb,
    const void* __restrict__ w1, const void* __restrict__ b1,
    const void* __restrict__ w2, const void* __restrict__ b2,
    const void* __restrict__ rw, const void* __restrict__ rb,
    const void* __restrict__ ow, const void* __restrict__ ob,
    const void* __restrict__ tw, const void* __restrict__ tb,
    const void* __restrict__ wc, const void* __restrict__ we,
    float* __restrict__ ws) {
  __shared__ float shpool[SH_END];
  __shared__ float sh1[64];
  __shared__ float sh2[64];
  __shared__ float shr[4];
  __shared__ float shcwe[512];
  bool f32m = sniff_f32(inp);
  int b = blockIdx.x, t = threadIdx.x;
  unsigned* wsu = (unsigned*)ws;

  if (b < 256) {
    // ---- encoder conv 3->64: block = (channel-group g, 256-px tile) ----
    int g = b >> 6;                 // oc [g*16, g*16+16)
    int px = (b & 63)*256 + t;
    float* shw = shpool;            // 432
    float* shb = shpool + 432;      // 16
    for (int i = t; i < 432; i += 256) shw[i] = rdw(encw, g*432 + i, f32m);
    if (t < 16) shb[t] = rdw(encb, g*16 + t, f32m);
    __syncthreads();
    int x = px & 127, y = px >> 7;
    float tp[27];
    #pragma unroll
    for (int ic = 0; ic < 3; ic++)
      #pragma unroll
      for (int dy = 0; dy < 3; dy++) {
        int yy = y + dy - 1;
        #pragma unroll
        for (int dx = 0; dx < 3; dx++) {
          int xx = x + dx - 1;
          bool ok = (yy >= 0) & (yy < 128) & (xx >= 0) & (xx < 128);
          tp[ic*9 + dy*3 + dx] = ok ? rdin(inp, ic*16384 + yy*128 + xx, f32m) : 0.0f;
        }
      }
    unsigned e[8];
    #pragma unroll
    for (int o4 = 0; o4 < 4; o4++) {
      float a[4];
      #pragma unroll
      for (int oo = 0; oo < 4; oo++) {
        int o2 = o4*4 + oo;
        float acc = shb[o2];
        #pragma unroll
        for (int kk = 0; kk < 27; kk++) acc = fmaf(shw[o2*27 + kk], tp[kk], acc);
        a[oo] = acc;
      }
      e[o4*2]   = pkh(a[0], a[1]);
      e[o4*2+1] = pkh(a[2], a[3]);
    }
    uint4* outp = (uint4*)(wsu + O_FEAT + px*32 + g*8);
    outp[0] = make_uint4(e[0], e[1], e[2], e[3]);
    outp[1] = make_uint4(e[4], e[5], e[6], e[7]);
  } else if (b < 272) {
    // ---- per-class MLP -> off, r; fold into CWC2 / W2P (weights LDS-staged) ----
    int cls = b - 256;
    for (int i = t; i < 4096; i += 256) shpool[SH_W2T + (i & 63)*65 + (i >> 6)] = rdw(w2, i, f32m);
    for (int i = t; i < 2048; i += 256) { shpool[SH_WE + i] = rdw(we, i, f32m); shpool[SH_WC + i] = rdw(wc, i, f32m); }
    for (int i = t; i < 1728; i += 256) shpool[SH_TW + i] = rdw(tw, i, f32m);
    for (int i = t; i < 128; i += 256)  shpool[SH_OW + i] = rdw(ow, i, f32m);
    for (int i = t; i < 256; i += 256)  shpool[SH_RW + i] = rdw(rw, i, f32m);
    if (t < 64) {
      float mcls = (float)(cls >> 2), ncls = (float)(cls & 3);
      float chv = (mcls + 0.5f)*0.25f - 0.5f;
      float cwv = (ncls + 0.5f)*0.25f - 0.5f;
      float s1 = rdw(w1,t*4+0,f32m)*0.25f + rdw(w1,t*4+1,f32m)*0.25f
               + rdw(w1,t*4+2,f32m)*chv + rdw(w1,t*4+3,f32m)*cwv + rdw(b1,t,f32m);
      sh1[t] = fmaxf(s1, 0.0f);
    }
    __syncthreads();
    if (t < 64) {
      float s2 = rdw(b2,t,f32m);
      for (int i = 0; i < 64; i++) s2 = fmaf(shpool[SH_W2T + i*65 + t], sh1[i], s2);
      sh2[t] = fmaxf(s2, 0.0f);
    }
    __syncthreads();
    if (t < 2) {
      float a = rdw(ob,t,f32m);
      for (int i = 0; i < 64; i++) a = fmaf(shpool[SH_OW + t*64 + i], sh2[i], a);
      ws[O_OFFTAB + cls*2 + t] = a;
    } else if (t < 6) {
      int e = t - 2;
      float a = rdw(rb,e,f32m);
      for (int i = 0; i < 64; i++) a = fmaf(shpool[SH_RW + e*64 + i], sh2[i], a);
      shr[e] = 1.0f / (1.0f + expf(-a));
    }
    __syncthreads();
    float r0 = shr[0], r1 = shr[1], r2 = shr[2], r3 = shr[3];
    for (int idx = t; idx < 512; idx += 256) {
      float a =       r0 * shpool[SH_WE + idx];
      a = fmaf(r1, shpool[SH_WE +  512 + idx], a);
      a = fmaf(r2, shpool[SH_WE + 1024 + idx], a);
      a = fmaf(r3, shpool[SH_WE + 1536 + idx], a);
      shcwe[idx] = a;
    }
    unsigned* wcw = wsu + O_CWC2 + cls*256;
    for (int idx = t; idx < 256; idx += 256) {
      int cp = idx >> 3, k = idx & 7;
      float lo =       r0 * shpool[SH_WC +        k*64 + 2*cp];
      lo = fmaf(r1, shpool[SH_WC +  512 + k*64 + 2*cp], lo);
      lo = fmaf(r2, shpool[SH_WC + 1024 + k*64 + 2*cp], lo);
      lo = fmaf(r3, shpool[SH_WC + 1536 + k*64 + 2*cp], lo);
      float hi =       r0 * shpool[SH_WC +        k*64 + 2*cp + 1];
      hi = fmaf(r1, shpool[SH_WC +  512 + k*64 + 2*cp + 1], hi);
      hi = fmaf(r2, shpool[SH_WC + 1024 + k*64 + 2*cp + 1], hi);
      hi = fmaf(r3, shpool[SH_WC + 1536 + k*64 + 2*cp + 1], hi);
      wcw[idx] = pkh(lo, hi);
    }
    __syncthreads();
    unsigned* wpp = wsu + O_W2P;
    for (int idx = t; idx < 108; idx += 256) {
      int j = idx / 12, rem = idx - j*12, o2 = rem >> 2, kp = rem & 3;
      float alo = 0.0f, ahi = 0.0f;
      for (int c = 0; c < 64; c++) {
        float tv = shpool[SH_TW + (o2*64 + c)*9 + j];
        alo = fmaf(tv, shcwe[c*8 + 2*kp],     alo);
        ahi = fmaf(tv, shcwe[c*8 + 2*kp + 1], ahi);
      }
      wpp[(cls*9 + j)*12 + o2*4 + kp] = pkh(alo, ahi);
    }
  } else {
    for (int idx = t; idx < 864; idx += 256) {
      int o2 = idx / 288, rem = idx - o2*288, j = rem >> 5, cp = rem & 31;
      unsigned d = pkh(rdw(tw, (o2*64 + 2*cp    )*9 + j, f32m),
                       rdw(tw, (o2*64 + 2*cp + 1)*9 + j, f32m));
      (wsu + O_TW2)[idx] = d;
    }
    if (t < 3) ws[O_TB + t] = rdin(tb, t, f32m);
  }
}

// ==== K2: fused main+tail, tile 8x16, halo 10x18, CWC2+W2P staged in LDS ====
// shd row: dwords 0..31 = fc f16 pairs (64 ch), 32..35 = mid f16 pairs. stride 36 dw.
__global__ __launch_bounds__(256) void k_maintail(const float* __restrict__ ws, unsigned* __restrict__ pred4) {
  __shared__ __align__(16) unsigned shd[180*36];   // 25920 B
  __shared__ __align__(16) unsigned shcw[32*132];  // 16896 B: CWC2, combo=cls*2+q, 132-dw rows
  __shared__ __align__(16) unsigned shw2p[1728];   // 6912 B: W2P all classes [cls][j][o][kpair]
  __shared__ unsigned short scls[180];
  __shared__ float spart[128*3];
  const unsigned* wsu = (const unsigned*)ws;
  int blk = blockIdx.x;                            // 0..2047
  int xcd = blk & 7, local = blk >> 3;             // XCD-banded for L2 locality
  int ty0 = (xcd*8 + (local >> 5)) * 8;
  int tx0 = (local & 31) * 16;
  int t = threadIdx.x;
  int q = t & 1;                                   // channel-half (32 ch each)
  const uint4* F2 = (const uint4*)(wsu + O_FEAT);

  // stage CWC2 (16 KB, bank-padded rows) + W2P (6.9 KB) into LDS
  {
    const uint4* src = (const uint4*)(wsu + O_CWC2);
    #pragma unroll
    for (int k = 0; k < 4; k++) {
      int e = t + k*256;                 // 0..1023 uint4s
      int combo = e >> 5, idx = e & 31;
      ((uint4*)&shcw[combo*132])[idx] = src[e];
    }
    const uint4* srcw = (const uint4*)(wsu + O_W2P);
    uint4* dstw = (uint4*)shw2p;
    if (t < 216) { dstw[t] = srcw[t]; dstw[t + 216] = srcw[t + 216]; }
  }
  __syncthreads();

  for (int s0 = 0; s0 < 256; s0 += 128) {
    int s = s0 + (t >> 1);
    if (s >= 180) continue;
    int cls = 0;
    #pragma unroll
    for (int i = 1; i < 16; i++) cls += (s >= PREF2[i]) ? 1 : 0;
    int j = s - PREF2[cls];
    int a = cls >> 2, bb = cls & 3;
    int nx = ((bb == 0) | (bb == 3)) ? 5 : 4;
    int jy = (nx == 4) ? (j >> 2) : ((j*13) >> 6);
    int jx = j - jy*nx;
    int py = ((a + 1) & 3) + 4*jy;
    int px = ((bb + 1) & 3) + 4*jx;
    int pos = py*18 + px;
    unsigned* row = &shd[pos*36 + q*16];
    int gy = ty0 - 1 + py, gx = tx0 - 1 + px;
    if ((gy < 0) | (gy >= HS) | (gx < 0) | (gx >= WSZ)) {
      if (q == 0) scls[pos] = 0;
      ((uint4*)row)[0] = make_uint4(0,0,0,0);
      ((uint4*)row)[1] = make_uint4(0,0,0,0);
      ((uint4*)row)[2] = make_uint4(0,0,0,0);
      ((uint4*)row)[3] = make_uint4(0,0,0,0);
      shd[pos*36 + 32 + q*2 + 0] = 0u;
      shd[pos*36 + 32 + q*2 + 1] = 0u;
      continue;
    }
    if (q == 0) scls[pos] = (unsigned short)cls;
    float off0 = ws[O_OFFTAB + cls*2 + 0];
    float off1 = ws[O_OFFTAB + cls*2 + 1];
    float gxf = (((float)gx + 0.5f)*0.25f - 0.5f)*(2.0f/127.0f) - 1.0f + off0*(2.0f/127.0f);
    float gyf = (((float)gy + 0.5f)*0.25f - 0.5f)*(2.0f/127.0f) - 1.0f + off1*(2.0f/127.0f);
    float sx = (gxf + 1.0f)*0.5f*127.0f;
    float sy = (gyf + 1.0f)*0.5f*127.0f;
    float x0f = floorf(sx), y0f = floorf(sy);
    float fx = sx - x0f, fy = sy - y0f;
    int ix0 = (int)x0f, iy0 = (int)y0f;
    int ix1 = ix0 + 1, iy1 = iy0 + 1;
    float wx0 = 1.0f - fx, wy0 = 1.0f - fy;
    float w00 = wy0*wx0, w01 = wy0*fx, w10 = fy*wx0, w11 = fy*fx;
    bool vx0 = (ix0 >= 0) & (ix0 < WW), vx1 = (ix1 >= 0) & (ix1 < WW);
    bool vy0 = (iy0 >= 0) & (iy0 < HH), vy1 = (iy1 >= 0) & (iy1 < HH);
    if (!(vy0 & vx0)) w00 = 0.0f;
    if (!(vy0 & vx1)) w01 = 0.0f;
    if (!(vy1 & vx0)) w10 = 0.0f;
    if (!(vy1 & vx1)) w11 = 0.0f;
    int cx0 = min(max(ix0, 0), WW-1), cx1 = min(max(ix1, 0), WW-1);
    int cy0 = min(max(iy0, 0), HH-1), cy1 = min(max(iy1, 0), HH-1);
    int b00 = (cy0*WW + cx0)*8 + q*4, b01 = (cy0*WW + cx1)*8 + q*4;
    int b10 = (cy1*WW + cx0)*8 + q*4, b11 = (cy1*WW + cx1)*8 + q*4;

    // batch all 16 tap loads (forced wide load window)
    uint4 A0 = F2[b00+0], A1 = F2[b00+1], A2 = F2[b00+2], A3 = F2[b00+3];
    uint4 B0 = F2[b01+0], B1 = F2[b01+1], B2 = F2[b01+2], B3 = F2[b01+3];
    uint4 C0 = F2[b10+0], C1 = F2[b10+1], C2 = F2[b10+2], C3 = F2[b10+3];
    uint4 D0 = F2[b11+0], D1 = F2[b11+1], D2 = F2[b11+2], D3 = F2[b11+3];

    h2 W00 = { (__fp16)w00, (__fp16)w00 };
    h2 W01 = { (__fp16)w01, (__fp16)w01 };
    h2 W10 = { (__fp16)w10, (__fp16)w10 };
    h2 W11 = { (__fp16)w11, (__fp16)w11 };

    unsigned fp[16];
    fp[ 0] = blend4(A0.x,B0.x,C0.x,D0.x,W00,W01,W10,W11);
    fp[ 1] = blend4(A0.y,B0.y,C0.y,D0.y,W00,W01,W10,W11);
    fp[ 2] = blend4(A0.z,B0.z,C0.z,D0.z,W00,W01,W10,W11);
    fp[ 3] = blend4(A0.w,B0.w,C0.w,D0.w,W00,W01,W10,W11);
    fp[ 4] = blend4(A1.x,B1.x,C1.x,D1.x,W00,W01,W10,W11);
    fp[ 5] = blend4(A1.y,B1.y,C1.y,D1.y,W00,W01,W10,W11);
    fp[ 6] = blend4(A1.z,B1.z,C1.z,D1.z,W00,W01,W10,W11);
    fp[ 7] = blend4(A1.w,B1.w,C1.w,D1.w,W00,W01,W10,W11);
    fp[ 8] = blend4(A2.x,B2.x,C2.x,D2.x,W00,W01,W10,W11);
    fp[ 9] = blend4(A2.y,B2.y,C2.y,D2.y,W00,W01,W10,W11);
    fp[10] = blend4(A2.z,B2.z,C2.z,D2.z,W00,W01,W10,W11);
    fp[11] = blend4(A2.w,B2.w,C2.w,D2.w,W00,W01,W10,W11);
    fp[12] = blend4(A3.x,B3.x,C3.x,D3.x,W00,W01,W10,W11);
    fp[13] = blend4(A3.y,B3.y,C3.y,D3.y,W00,W01,W10,W11);
    fp[14] = blend4(A3.z,B3.z,C3.z,D3.z,W00,W01,W10,W11);
    fp[15] = blend4(A3.w,B3.w,C3.w,D3.w,W00,W01,W10,W11);

    ((uint4*)row)[0] = make_uint4(fp[0],  fp[1],  fp[2],  fp[3]);
    ((uint4*)row)[1] = make_uint4(fp[4],  fp[5],  fp[6],  fp[7]);
    ((uint4*)row)[2] = make_uint4(fp[8],  fp[9],  fp[10], fp[11]);
    ((uint4*)row)[3] = make_uint4(fp[12], fp[13], fp[14], fp[15]);

    // mid from bank-padded LDS CWC2
    const uint4* CWv = (const uint4*)&shcw[(cls*2 + q)*132];
    float mid[8] = {0,0,0,0,0,0,0,0};
    #pragma unroll
    for (int i = 0; i < 16; i++) {
      uint4 w0 = CWv[i*2], w1 = CWv[i*2+1];
      h2 f = uh(fp[i]);
      mid[0] = FDOT2(f, uh(w0.x), mid[0]); mid[1] = FDOT2(f, uh(w0.y), mid[1]);
      mid[2] = FDOT2(f, uh(w0.z), mid[2]); mid[3] = FDOT2(f, uh(w0.w), mid[3]);
      mid[4] = FDOT2(f, uh(w1.x), mid[4]); mid[5] = FDOT2(f, uh(w1.y), mid[5]);
      mid[6] = FDOT2(f, uh(w1.z), mid[6]); mid[7] = FDOT2(f, uh(w1.w), mid[7]);
    }
    #pragma unroll
    for (int k = 0; k < 8; k++) mid[k] += __shfl_xor(mid[k], 1);
    shd[pos*36 + 32 + q*2 + 0] = pkh(mid[q*4+0], mid[q*4+1]);
    shd[pos*36 + 32 + q*2 + 1] = pkh(mid[q*4+2], mid[q*4+3]);
  }
  __syncthreads();

  // ---- tail: 2-way wave-uniform split over channel halves; mid j-split ----
  int half = t >> 7, pi = t & 127;
  int tx = pi & 15, ty = pi >> 4;
  const unsigned* TW2 = wsu + O_TW2;
  float a0, a1, a2;
  if (half == 0) { a0 = ws[O_TB+0]; a1 = ws[O_TB+1]; a2 = ws[O_TB+2]; }
  else           { a0 = 0.0f; a1 = 0.0f; a2 = 0.0f; }
  int cb = half*16;
  #pragma unroll
  for (int j = 0; j < 9; j++) {
    int dy = j / 3, dx = j - dy*3;
    int pp = (ty + dy)*18 + (tx + dx);
    const uint4* frow = (const uint4*)&shd[pp*36 + half*16];
    uint4 f0 = frow[0], f1 = frow[1], f2 = frow[2], f3 = frow[3];
    const unsigned* T0 = TW2 + (0*9+j)*32 + cb;
    const unsigned* T1 = TW2 + (1*9+j)*32 + cb;
    const unsigned* T2 = TW2 + (2*9+j)*32 + cb;
    a0=FDOT2(uh(f0.x),uh(T0[0]),a0); a0=FDOT2(uh(f0.y),uh(T0[1]),a0); a0=FDOT2(uh(f0.z),uh(T0[2]),a0); a0=FDOT2(uh(f0.w),uh(T0[3]),a0);
    a0=FDOT2(uh(f1.x),uh(T0[4]),a0); a0=FDOT2(uh(f1.y),uh(T0[5]),a0); a0=FDOT2(uh(f1.z),uh(T0[6]),a0); a0=FDOT2(uh(f1.w),uh(T0[7]),a0);
    a0=FDOT2(uh(f2.x),uh(T0[8]),a0); a0=FDOT2(uh(f2.y),uh(T0[9]),a0); a0=FDOT2(uh(f2.z),uh(T0[10]),a0); a0=FDOT2(uh(f2.w),uh(T0[11]),a0);
    a0=FDOT2(uh(f3.x),uh(T0[12]),a0); a0=FDOT2(uh(f3.y),uh(T0[13]),a0); a0=FDOT2(uh(f3.z),uh(T0[14]),a0); a0=FDOT2(uh(f3.w),uh(T0[15]),a0);
    a1=FDOT2(uh(f0.x),uh(T1[0]),a1); a1=FDOT2(uh(f0.y),uh(T1[1]),a1); a1=FDOT2(uh(f0.z),uh(T1[2]),a1); a1=FDOT2(uh(f0.w),uh(T1[3]),a1);
    a1=FDOT2(uh(f1.x),uh(T1[4]),a1); a1=FDOT2(uh(f1.y),uh(T1[5]),a1); a1=FDOT2(uh(f1.z),uh(T1[6]),a1); a1=FDOT2(uh(f1.w),uh(T1[7]),a1);
    a1=FDOT2(uh(f2.x),uh(T1[8]),a1); a1=FDOT2(uh(f2.y),uh(T1[9]),a1); a1=FDOT2(uh(f2.z),uh(T1[10]),a1); a1=FDOT2(uh(f2.w),uh(T1[11]),a1);
    a1=FDOT2(uh(f3.x),uh(T1[12]),a1); a1=FDOT2(uh(f3.y),uh(T1[13]),a1); a1=FDOT2(uh(f3.z),uh(T1[14]),a1); a1=FDOT2(uh(f3.w),uh(T1[15]),a1);
    a2=FDOT2(uh(f0.x),uh(T2[0]),a2); a2=FDOT2(uh(f0.y),uh(T2[1]),a2); a2=FDOT2(uh(f0.z),uh(T2[2]),a2); a2=FDOT2(uh(f0.w),uh(T2[3]),a2);
    a2=FDOT2(uh(f1.x),uh(T2[4]),a2); a2=FDOT2(uh(f1.y),uh(T2[5]),a2); a2=FDOT2(uh(f1.z),uh(T2[6]),a2); a2=FDOT2(uh(f1.w),uh(T2[7]),a2);
    a2=FDOT2(uh(f2.x),uh(T2[8]),a2); a2=FDOT2(uh(f2.y),uh(T2[9]),a2); a2=FDOT2(uh(f2.z),uh(T2[10]),a2); a2=FDOT2(uh(f2.w),uh(T2[11]),a2);
    a2=FDOT2(uh(f3.x),uh(T2[12]),a2); a2=FDOT2(uh(f3.y),uh(T2[13]),a2); a2=FDOT2(uh(f3.z),uh(T2[14]),a2); a2=FDOT2(uh(f3.w),uh(T2[15]),a2);
    // mid part split by j: half0 j 0..4, half1 j 5..8 (W2P from LDS)
    bool mine = (half == 0) ? (j < 5) : (j >= 5);
    if (mine) {
      int cl = scls[pp];
      uint4 mv = *(const uint4*)&shd[pp*36 + 32];
      const uint4* Wp = (const uint4*)shw2p + (cl*9 + j)*3;
      uint4 w0 = Wp[0], w1 = Wp[1], w2 = Wp[2];
      h2 m0 = uh(mv.x), m1 = uh(mv.y), m2 = uh(mv.z), m3 = uh(mv.w);
      a0 = FDOT2(m0, uh(w0.x), a0); a0 = FDOT2(m1, uh(w0.y), a0);
      a0 = FDOT2(m2, uh(w0.z), a0); a0 = FDOT2(m3, uh(w0.w), a0);
      a1 = FDOT2(m0, uh(w1.x), a1); a1 = FDOT2(m1, uh(w1.y), a1);
      a1 = FDOT2(m2, uh(w1.z), a1); a1 = FDOT2(m3, uh(w1.w), a1);
      a2 = FDOT2(m0, uh(w2.x), a2); a2 = FDOT2(m1, uh(w2.y), a2);
      a2 = FDOT2(m2, uh(w2.z), a2); a2 = FDOT2(m3, uh(w2.w), a2);
    }
  }
  if (half == 1) {
    spart[pi*3+0] = a0; spart[pi*3+1] = a1; spart[pi*3+2] = a2;
  }
  __syncthreads();
  if (half == 0) {
    a0 += spart[pi*3+0]; a1 += spart[pi*3+1]; a2 += spart[pi*3+2];
    ((uint2*)pred4)[blk*128 + pi] = make_uint2(pkbf(a0, a1), pkbf(a2, 0.0f));
  }
}

// ==== K3: query gather ====
__global__ __launch_bounds__(256) void k_gather(const void* __restrict__ inp,
                                                const void* __restrict__ coord, const void* __restrict__ cell,
                                                const float* __restrict__ ws, void* __restrict__ outp) {
  bool f32m = sniff_f32(inp);
  const uint2* pred4 = (const uint2*)((const unsigned*)ws + O_PRED);
  int q = blockIdx.x*256 + threadIdx.x;
  float cy, cx, ly, lx;
  if (f32m) {
    float2 c = ((const float2*)coord)[q]; cy = c.x; cx = c.y;
    float2 l = ((const float2*)cell)[q];  ly = l.x; lx = l.y;
  } else {
    unsigned cu = ((const unsigned*)coord)[q]; cy = asf(cu<<16); cx = asf(cu & 0xffff0000u);
    unsigned lu = ((const unsigned*)cell)[q];  ly = asf(lu<<16); lx = asf(lu & 0xffff0000u);
  }
  float gyq = fminf(fmaxf(cy - ly*0.5f + 1e-6f, -1.0f + 1e-6f), 1.0f - 1e-6f);
  float gxq = fminf(fmaxf(cx - lx*0.5f + 1e-6f, -1.0f + 1e-6f), 1.0f - 1e-6f);
  int xi = (int)rintf((gxq + 1.0f)*0.5f*511.0f);
  int yi = (int)rintf((gyq + 1.0f)*0.5f*511.0f);
  xi = min(max(xi, 0), WSZ-1);
  yi = min(max(yi, 0), HS-1);
  // invert 8x16 block-sorted layout (row-major pixels within tile)
  int row = yi >> 3, col = xi >> 4;
  int xcd = row >> 3;
  int local = (row & 7)*32 + col;
  int blk = local*8 + xcd;
  int pi = (yi & 7)*16 + (xi & 15);
  uint2 d = pred4[blk*128 + pi];
  float v0 = asf(d.x << 16), v1 = asf(d.x & 0xffff0000u), v2 = asf(d.y << 16);
  if (f32m) {
    float* o = (float*)outp;
    o[q*3 + 0] = v0; o[q*3 + 1] = v1; o[q*3 + 2] = v2;
  } else {
    bf16* o = (bf16*)outp;
    o[q*3 + 0] = __float2bfloat16(v0);
    o[q*3 + 1] = __float2bfloat16(v1);
    o[q*3 + 2] = __float2bfloat16(v2);
  }
}

extern "C" void kernel_launch(void* const* d_in, const int* in_sizes, int n_in,
                              void* d_out, int out_size, void* d_ws, size_t ws_size,
                              hipStream_t stream) {
  const void* inp   = d_in[0];
  const void* coord = d_in[1];
  const void* cell  = d_in[2];
  const void* encw  = d_in[3];
  const void* encb  = d_in[4];
  const void* w1    = d_in[5];
  const void* b1    = d_in[6];
  const void* w2    = d_in[7];
  const void* b2    = d_in[8];
  const void* rw    = d_in[9];
  const void* rb    = d_in[10];
  const void* ow    = d_in[11];
  const void* ob    = d_in[12];
  const void* tw    = d_in[13];
  const void* tb    = d_in[14];
  const void* wc    = d_in[15];
  const void* we    = d_in[16];

  float* wsf = (float*)d_ws;
  unsigned* pred4 = (unsigned*)wsf + O_PRED;

  k_prep<<<273, 256, 0, stream>>>(inp, encw, encb, w1, b1, w2, b2, rw, rb, ow, ob, tw, tb, wc, we, wsf);
  k_maintail<<<2048, 256, 0, stream>>>(wsf, pred4);
  k_gather<<<1024, 256, 0, stream>>>(inp, coord, cell, wsf, d_out);
}